// Round 1
// baseline (188.952 us; speedup 1.0000x reference)
//
#include <hip/hip_runtime.h>

// ============================================================================
// SelfAttentionLayer (RPE attention), MI355X bf16-MFMA implementation.
// Pipeline: cvt_all -> rpe_cvt -> gemm_proj(z=0..3: q,k,v,qt) ->
//           attn (flash-style, no-max softmax, in-LDS qrpe table) ->
//           gemm_wo (+qt residual, in-place) -> ln.
// Workspace need: ~47 MB (guarded).
// ============================================================================

typedef short          bf16x8 __attribute__((ext_vector_type(8)));
typedef float          f32x4  __attribute__((ext_vector_type(4)));
typedef int            i32x4  __attribute__((ext_vector_type(4)));
typedef unsigned short u16x4  __attribute__((ext_vector_type(4)));
typedef unsigned short u16x8  __attribute__((ext_vector_type(8)));

#define SEQ 2048
#define EMB 1024
#define NH  16
#define HD  64
#define RL  512

#define MFMA16(a,b,c) __builtin_amdgcn_mfma_f32_16x16x32_bf16((a),(b),(c),0,0,0)

__device__ __forceinline__ unsigned short f2bf(float f){
  union{float f; unsigned u;} x; x.f=f;
  unsigned r = x.u + 0x7FFFu + ((x.u>>16)&1u);
  return (unsigned short)(r>>16);
}
__device__ __forceinline__ float bf2f(unsigned short u){
  union{unsigned u; float f;} x; x.u=((unsigned)u)<<16; return x.f;
}
__device__ __forceinline__ unsigned pack2(float a, float b){
  return (unsigned)f2bf(a) | ((unsigned)f2bf(b)<<16);
}
__device__ __forceinline__ void gload16(const void* g, void* l){
  __builtin_amdgcn_global_load_lds((const __attribute__((address_space(1))) unsigned int*)g,
                                   (__attribute__((address_space(3))) unsigned int*)l, 16, 0, 0);
}
// 16B fragment read from a [rows][64]-bf16 LDS tile with per-8-row XOR swizzle.
// chunk = which 16B block (0..7) along the 128B row; staging applied same XOR.
__device__ __forceinline__ bf16x8 fragld(const unsigned short* t, int row, int chunk){
  int swz = chunk ^ (row & 7);
  return *(const bf16x8*)(t + row*64 + swz*8);
}

// ---------------------------------------------------------------------------
// f32 -> bf16 conversions: y=0..2: query,key,value (2M); y=3..7: Wq,Wk,Wv,Wqt,Wo (1M)
// ---------------------------------------------------------------------------
__global__ __launch_bounds__(256) void cvt_all(
    const float* __restrict__ s0, const float* __restrict__ s1, const float* __restrict__ s2,
    const float* __restrict__ s3, const float* __restrict__ s4, const float* __restrict__ s5,
    const float* __restrict__ s6, const float* __restrict__ s7,
    unsigned short* __restrict__ d0, unsigned short* __restrict__ d1, unsigned short* __restrict__ d2,
    unsigned short* __restrict__ d3, unsigned short* __restrict__ d4, unsigned short* __restrict__ d5,
    unsigned short* __restrict__ d6, unsigned short* __restrict__ d7)
{
  const float* s; unsigned short* d; int n;
  switch (blockIdx.y) {
    case 0: s=s0; d=d0; n=SEQ*EMB; break;
    case 1: s=s1; d=d1; n=SEQ*EMB; break;
    case 2: s=s2; d=d2; n=SEQ*EMB; break;
    case 3: s=s3; d=d3; n=EMB*EMB; break;
    case 4: s=s4; d=d4; n=EMB*EMB; break;
    case 5: s=s5; d=d5; n=EMB*EMB; break;
    case 6: s=s6; d=d6; n=EMB*EMB; break;
    default: s=s7; d=d7; n=EMB*EMB; break;
  }
  int i = (blockIdx.x*256 + threadIdx.x)*8;
  if (i >= n) return;
  f32x4 a = *(const f32x4*)(s+i);
  f32x4 b = *(const f32x4*)(s+i+4);
  u16x8 o;
  #pragma unroll
  for (int j=0;j<4;++j){ o[j]=f2bf(a[j]); o[4+j]=f2bf(b[j]); }
  *(u16x8*)(d+i) = o;
}

// rpe [l][h][d] f32 -> [h][l][d] bf16
__global__ __launch_bounds__(256) void rpe_cvt(const float* __restrict__ src,
                                               unsigned short* __restrict__ dst)
{
  int i = (blockIdx.x*256 + threadIdx.x)*4;   // over RL*NH*HD = 524288
  int l = i >> 10;
  int h = (i >> 6) & 15;
  int d = i & 63;
  f32x4 a = *(const f32x4*)(src + i);
  u16x4 o;
  #pragma unroll
  for (int j=0;j<4;++j) o[j]=f2bf(a[j]);
  *(u16x4*)(dst + ((size_t)h*RL + l)*HD + d) = o;
}

// ---------------------------------------------------------------------------
// GEMM core: C[128x128] = A[M,1024] @ W[N,1024]^T  (bf16 in, f32 acc)
// 256 threads = 4 waves (2x2 of 64x64). global_load_lds staging, XOR swizzle.
// ---------------------------------------------------------------------------
__device__ __forceinline__ void gemm_core(const unsigned short* __restrict__ A,
                                          const unsigned short* __restrict__ W,
                                          unsigned short* At, unsigned short* Wt,
                                          f32x4 acc[4][4], int m0, int n0)
{
  const int tid = threadIdx.x, lane = tid & 63, w = tid >> 6;
  const int rg = lane >> 3, sc = (lane & 7) ^ rg;
  const int c = lane & 15, g = lane >> 4;
  const int wm = w >> 1, wn = w & 1;

  for (int kt = 0; kt < EMB/64; ++kt) {
    __syncthreads();
    #pragma unroll
    for (int i = 0; i < 4; ++i) {
      int r = w*32 + i*8 + rg;
      gload16(A + (size_t)(m0+r)*EMB + kt*64 + sc*8, At + (w*32 + i*8)*64);
      gload16(W + (size_t)(n0+r)*EMB + kt*64 + sc*8, Wt + (w*32 + i*8)*64);
    }
    __syncthreads();
    #pragma unroll
    for (int kk = 0; kk < 2; ++kk) {
      bf16x8 af[4], bw[4];
      #pragma unroll
      for (int mf = 0; mf < 4; ++mf) af[mf] = fragld(At, wm*64 + mf*16 + c, kk*4 + g);
      #pragma unroll
      for (int nf = 0; nf < 4; ++nf) bw[nf] = fragld(Wt, wn*64 + nf*16 + c, kk*4 + g);
      #pragma unroll
      for (int mf = 0; mf < 4; ++mf)
        #pragma unroll
        for (int nf = 0; nf < 4; ++nf)
          acc[mf][nf] = MFMA16(af[mf], bw[nf], acc[mf][nf]);
    }
  }
}

// Fused projections. z: 0=Q(scaled), 1=K, 2=V(transposed out), 3=QT(f32 out)
__global__ __launch_bounds__(256) void gemm_proj(
    const unsigned short* __restrict__ Aq, const unsigned short* __restrict__ Ak,
    const unsigned short* __restrict__ Av,
    const unsigned short* __restrict__ Wq, const unsigned short* __restrict__ Wk,
    const unsigned short* __restrict__ Wv, const unsigned short* __restrict__ Wqt,
    const float* __restrict__ bq, const float* __restrict__ bk,
    const float* __restrict__ bv, const float* __restrict__ bqt,
    unsigned short* __restrict__ q_out, unsigned short* __restrict__ k_out,
    unsigned short* __restrict__ vt_out, float* __restrict__ qt_out)
{
  __shared__ alignas(16) unsigned short At[128*64];
  __shared__ alignas(16) unsigned short Wt[128*64];
  const unsigned short *A, *W; const float* bias;
  const int z = blockIdx.z;
  if      (z == 0) { A=Aq; W=Wq;  bias=bq;  }
  else if (z == 1) { A=Ak; W=Wk;  bias=bk;  }
  else if (z == 2) { A=Av; W=Wv;  bias=bv;  }
  else             { A=Aq; W=Wqt; bias=bqt; }

  f32x4 acc[4][4];
  #pragma unroll
  for (int i=0;i<4;++i)
    #pragma unroll
    for (int j=0;j<4;++j) acc[i][j] = (f32x4){0.f,0.f,0.f,0.f};

  const int m0 = blockIdx.y*128, n0 = blockIdx.x*128;
  gemm_core(A, W, At, Wt, acc, m0, n0);

  const int lane = threadIdx.x & 63, w = threadIdx.x >> 6;
  const int c = lane & 15, g = lane >> 4, wm = w >> 1, wn = w & 1;
  #pragma unroll
  for (int nf = 0; nf < 4; ++nf) {
    int n = n0 + wn*64 + nf*16 + c;
    float b = bias[n];
    #pragma unroll
    for (int mf = 0; mf < 4; ++mf) {
      int mb = m0 + wm*64 + mf*16 + g*4;
      if (z == 0) {
        #pragma unroll
        for (int j=0;j<4;++j) q_out[(size_t)(mb+j)*EMB + n] = f2bf((acc[mf][nf][j] + b)*0.125f);
      } else if (z == 1) {
        #pragma unroll
        for (int j=0;j<4;++j) k_out[(size_t)(mb+j)*EMB + n] = f2bf(acc[mf][nf][j] + b);
      } else if (z == 2) {
        u16x4 pk;
        #pragma unroll
        for (int j=0;j<4;++j) pk[j] = f2bf(acc[mf][nf][j] + b);
        *(u16x4*)(vt_out + (size_t)n*SEQ + mb) = pk;     // V^T layout [n][s]
      } else {
        #pragma unroll
        for (int j=0;j<4;++j) qt_out[(size_t)(mb+j)*EMB + n] = acc[mf][nf][j] + b;
      }
    }
  }
}

// Output projection: qt[m][n] += att @ Wo^T + bo   (in-place residual)
__global__ __launch_bounds__(256) void gemm_wo(
    const unsigned short* __restrict__ A, const unsigned short* __restrict__ W,
    const float* __restrict__ bo, float* __restrict__ qt)
{
  __shared__ alignas(16) unsigned short At[128*64];
  __shared__ alignas(16) unsigned short Wt[128*64];
  f32x4 acc[4][4];
  #pragma unroll
  for (int i=0;i<4;++i)
    #pragma unroll
    for (int j=0;j<4;++j) acc[i][j] = (f32x4){0.f,0.f,0.f,0.f};
  const int m0 = blockIdx.y*128, n0 = blockIdx.x*128;
  gemm_core(A, W, At, Wt, acc, m0, n0);

  const int lane = threadIdx.x & 63, w = threadIdx.x >> 6;
  const int c = lane & 15, g = lane >> 4, wm = w >> 1, wn = w & 1;
  #pragma unroll
  for (int nf = 0; nf < 4; ++nf) {
    int n = n0 + wn*64 + nf*16 + c;
    float b = bo[n];
    #pragma unroll
    for (int mf = 0; mf < 4; ++mf) {
      int mb = m0 + wm*64 + mf*16 + g*4;
      #pragma unroll
      for (int j=0;j<4;++j) {
        size_t idx = (size_t)(mb+j)*EMB + n;
        qt[idx] = acc[mf][nf][j] + b + qt[idx];
      }
    }
  }
}

// ---------------------------------------------------------------------------
// Attention: block = (32 q-rows, 1 head), 2 waves (wave w owns q rows w*16..+15).
// Swapped QK^T (mfma(K,Q) -> S^T, q = lane&15), no-max softmax (logits bounded;
// masked lanes underflow exp->0), qrpe table built in LDS by MFMA prologue.
// ---------------------------------------------------------------------------
__global__ __launch_bounds__(128) void attn_kernel(
    const unsigned short* __restrict__ q_bf, const unsigned short* __restrict__ k_bf,
    const unsigned short* __restrict__ vt_bf, const unsigned short* __restrict__ rpe_bf,
    const int* __restrict__ pos, const float* __restrict__ mask,
    unsigned short* __restrict__ att_out)
{
  __shared__ alignas(16) unsigned short q_tile[32*64];     // swizzled
  __shared__ alignas(16) unsigned short k_tile[64*64];     // swizzled (also rpe chunks)
  __shared__ alignas(16) unsigned short vt_tile[64*64];    // swizzled, rows = d
  __shared__ alignas(16) unsigned short table[32*520];     // qrpe[q][l], padded stride
  __shared__ alignas(16) unsigned short p_lds[2][16*72];   // per-wave P[q][k], stride 72

  const int tid = threadIdx.x, lane = tid & 63, w = tid >> 6;
  const int h = blockIdx.y;
  const int q0 = blockIdx.x * 32;
  const int rg = lane >> 3, sc = (lane & 7) ^ rg;
  const int c = lane & 15, g = lane >> 4;

  // stage Q tile (32 x 64)
  #pragma unroll
  for (int i = 0; i < 2; ++i) {
    int r = w*16 + i*8 + rg;
    gload16(q_bf + (size_t)(q0 + r)*EMB + h*HD + sc*8, q_tile + (w*16 + i*8)*64);
  }
  __syncthreads();

  // prologue: table[q][l] = q_row . rpe_l   (D[l][q] frags -> 4 consecutive l per lane)
  for (int ch = 0; ch < 8; ++ch) {
    __syncthreads();
    #pragma unroll
    for (int i = 0; i < 4; ++i) {
      int r = w*32 + i*8 + rg;
      gload16(rpe_bf + ((size_t)h*RL + ch*64 + r)*HD + sc*8, k_tile + (w*32 + i*8)*64);
    }
    __syncthreads();
    #pragma unroll
    for (int lf = 0; lf < 2; ++lf) {
      #pragma unroll
      for (int qh = 0; qh < 2; ++qh) {
        f32x4 dd = (f32x4){0.f,0.f,0.f,0.f};
        #pragma unroll
        for (int kk = 0; kk < 2; ++kk)
          dd = MFMA16(fragld(k_tile, w*32 + lf*16 + c, kk*4 + g),
                      fragld(q_tile, qh*16 + c,        kk*4 + g), dd);
        int lb = ch*64 + w*32 + lf*16 + g*4;
        int qq = qh*16 + c;
        u16x4 pk;
        #pragma unroll
        for (int j = 0; j < 4; ++j) pk[j] = f2bf(dd[j]);
        *(u16x4*)(table + qq*520 + lb) = pk;
      }
    }
  }
  __syncthreads();

  f32x4 oacc[4];
  #pragma unroll
  for (int i=0;i<4;++i) oacc[i] = (f32x4){0.f,0.f,0.f,0.f};
  float sump = 0.f;
  const bf16x8 qf0 = fragld(q_tile, w*16 + c, g);
  const bf16x8 qf1 = fragld(q_tile, w*16 + c, 4 + g);

  for (int kt = 0; kt < SEQ/64; ++kt) {
    const int kb = kt*64;
    __syncthreads();
    #pragma unroll
    for (int i = 0; i < 4; ++i) {
      int r = w*32 + i*8 + rg;
      gload16(k_bf  + (size_t)(kb + r)*EMB + h*HD + sc*8, k_tile  + (w*32 + i*8)*64);
      gload16(vt_bf + ((size_t)h*HD + r)*SEQ + kb + sc*8, vt_tile + (w*32 + i*8)*64);
    }
    __syncthreads();

    const int qg = q0 + w*16 + c;
    const int*   prow = pos  + (size_t)qg*SEQ + kb;
    const float* mrow = mask + (size_t)qg*SEQ + kb;

    #pragma unroll
    for (int kf = 0; kf < 4; ++kf) {
      f32x4 sf = (f32x4){0.f,0.f,0.f,0.f};
      sf = MFMA16(fragld(k_tile, kf*16 + c, g),     qf0, sf);
      sf = MFMA16(fragld(k_tile, kf*16 + c, 4 + g), qf1, sf);
      const int koff = kf*16 + g*4;                  // k-local of reg j=0
      i32x4 pv = *(const i32x4*)(prow + koff);
      f32x4 mv = *(const f32x4*)(mrow + koff);
      float pj[4];
      #pragma unroll
      for (int j = 0; j < 4; ++j) {
        float rv = bf2f(table[(w*16 + c)*520 + pv[j]]);
        float s  = sf[j] + rv - (1.0f - mv[j])*1.0e6f;
        pj[j] = __expf(s);
        sump += pj[j];
      }
      *(unsigned*)(&p_lds[w][c*72 + koff])     = pack2(pj[0], pj[1]);
      *(unsigned*)(&p_lds[w][c*72 + koff + 2]) = pack2(pj[2], pj[3]);
    }

    // same-wave LDS RAW: force write completion before fragment reads
    asm volatile("s_waitcnt lgkmcnt(0)" ::: "memory");

    #pragma unroll
    for (int kc = 0; kc < 2; ++kc) {
      bf16x8 pa = *(const bf16x8*)(&p_lds[w][c*72 + kc*32 + g*8]);
      #pragma unroll
      for (int df = 0; df < 4; ++df)
        oacc[df] = MFMA16(pa, fragld(vt_tile, df*16 + c, kc*4 + g), oacc[df]);
    }
  }

  sump += __shfl_xor(sump, 16);
  sump += __shfl_xor(sump, 32);

  #pragma unroll
  for (int j = 0; j < 4; ++j) {
    float sv  = __shfl(sump, g*4 + j);
    float inv = 1.0f / sv;
    int qrow = q0 + w*16 + g*4 + j;
    #pragma unroll
    for (int df = 0; df < 4; ++df)
      att_out[(size_t)qrow*EMB + h*HD + df*16 + c] = f2bf(oacc[df][j] * inv);
  }
}

// ---------------------------------------------------------------------------
// LayerNorm over rows of qt (f32), gamma/beta, -> d_out
// ---------------------------------------------------------------------------
__global__ __launch_bounds__(256) void ln_kernel(const float* __restrict__ x,
                                                 const float* __restrict__ gamma,
                                                 const float* __restrict__ beta,
                                                 float* __restrict__ out)
{
  const int row = blockIdx.x, t = threadIdx.x;
  f32x4 v = *(const f32x4*)(x + (size_t)row*EMB + t*4);
  float s = v[0]+v[1]+v[2]+v[3];
  #pragma unroll
  for (int o = 32; o > 0; o >>= 1) s += __shfl_xor(s, o);
  __shared__ float r1[4], r2[4];
  if ((t & 63) == 0) r1[t >> 6] = s;
  __syncthreads();
  float mean = (r1[0]+r1[1]+r1[2]+r1[3]) * (1.0f/EMB);
  f32x4 d; float q = 0.f;
  #pragma unroll
  for (int j=0;j<4;++j){ d[j] = v[j] - mean; q += d[j]*d[j]; }
  #pragma unroll
  for (int o = 32; o > 0; o >>= 1) q += __shfl_xor(q, o);
  if ((t & 63) == 0) r2[t >> 6] = q;
  __syncthreads();
  float var = (r2[0]+r2[1]+r2[2]+r2[3]) * (1.0f/EMB);
  float rs = rsqrtf(var + 1e-6f);
  f32x4 gg = *(const f32x4*)(gamma + t*4);
  f32x4 bb = *(const f32x4*)(beta  + t*4);
  f32x4 o4;
  #pragma unroll
  for (int j=0;j<4;++j) o4[j] = d[j]*rs*gg[j] + bb[j];
  *(f32x4*)(out + (size_t)row*EMB + t*4) = o4;
}

// ---------------------------------------------------------------------------
extern "C" void kernel_launch(void* const* d_in, const int* in_sizes, int n_in,
                              void* d_out, int out_size, void* d_ws, size_t ws_size,
                              hipStream_t stream)
{
  (void)in_sizes; (void)n_in; (void)out_size;
  const float* query = (const float*)d_in[0];
  const float* key   = (const float*)d_in[1];
  const float* value = (const float*)d_in[2];
  const int*   pos   = (const int*)  d_in[3];
  const float* mask  = (const float*)d_in[4];
  const float* Wq    = (const float*)d_in[5];
  const float* bq    = (const float*)d_in[6];
  const float* Wk    = (const float*)d_in[7];
  const float* bk    = (const float*)d_in[8];
  const float* Wv    = (const float*)d_in[9];
  const float* bv    = (const float*)d_in[10];
  const float* rpe   = (const float*)d_in[11];
  const float* Wqt   = (const float*)d_in[12];
  const float* bqt   = (const float*)d_in[13];
  const float* Wo    = (const float*)d_in[14];
  const float* bo    = (const float*)d_in[15];
  const float* gamma = (const float*)d_in[16];
  const float* beta  = (const float*)d_in[17];
  float* out = (float*)d_out;

  // workspace layout (bytes)
  char* ws = (char*)d_ws;
  const size_t OFF_QBF   = 0;          // q (scaled)   [2048][1024] bf16  4MB
  const size_t OFF_KBF   = 4194304;    // k            [2048][1024] bf16  4MB
  const size_t OFF_VTBF  = 8388608;    // v^T          [1024][2048] bf16  4MB
  const size_t OFF_QRYBF = 12582912;   // query bf16   4MB
  const size_t OFF_KEYBF = 16777216;   // key bf16     4MB
  const size_t OFF_VALBF = 20971520;   // value bf16   4MB
  const size_t OFF_WQ    = 25165824;   // 2MB each
  const size_t OFF_WK    = 27262976;
  const size_t OFF_WV    = 29360128;
  const size_t OFF_WQT   = 31457280;
  const size_t OFF_WO    = 33554432;
  const size_t OFF_RPE   = 35651584;   // [16][512][64] bf16  1MB
  const size_t OFF_QT    = 36700160;   // qt / pre-LN  [2048][1024] f32  8MB
  const size_t OFF_ATT   = 45088768;   // attention out bf16  4MB
  const size_t WS_NEED   = 49283072;
  if (ws_size < WS_NEED) return;  // visible failure instead of OOB writes

  unsigned short* q_bf   = (unsigned short*)(ws + OFF_QBF);
  unsigned short* k_bf   = (unsigned short*)(ws + OFF_KBF);
  unsigned short* vt_bf  = (unsigned short*)(ws + OFF_VTBF);
  unsigned short* qry_bf = (unsigned short*)(ws + OFF_QRYBF);
  unsigned short* key_bf = (unsigned short*)(ws + OFF_KEYBF);
  unsigned short* val_bf = (unsigned short*)(ws + OFF_VALBF);
  unsigned short* wq_bf  = (unsigned short*)(ws + OFF_WQ);
  unsigned short* wk_bf  = (unsigned short*)(ws + OFF_WK);
  unsigned short* wv_bf  = (unsigned short*)(ws + OFF_WV);
  unsigned short* wqt_bf = (unsigned short*)(ws + OFF_WQT);
  unsigned short* wo_bf  = (unsigned short*)(ws + OFF_WO);
  unsigned short* rpe_bf = (unsigned short*)(ws + OFF_RPE);
  float*          qt     = (float*)         (ws + OFF_QT);
  unsigned short* att_bf = (unsigned short*)(ws + OFF_ATT);

  cvt_all<<<dim3(1024, 8), 256, 0, stream>>>(
      query, key, value, Wq, Wk, Wv, Wqt, Wo,
      qry_bf, key_bf, val_bf, wq_bf, wk_bf, wv_bf, wqt_bf, wo_bf);
  rpe_cvt<<<512, 256, 0, stream>>>(rpe, rpe_bf);
  gemm_proj<<<dim3(8, 16, 4), 256, 0, stream>>>(
      qry_bf, key_bf, val_bf, wq_bf, wk_bf, wv_bf, wqt_bf,
      bq, bk, bv, bqt, q_bf, k_bf, vt_bf, qt);
  attn_kernel<<<dim3(SEQ/32, NH), 128, 0, stream>>>(
      q_bf, k_bf, vt_bf, rpe_bf, pos, mask, att_bf);
  gemm_wo<<<dim3(8, 16), 256, 0, stream>>>(att_bf, wo_bf, bo, qt);
  ln_kernel<<<2048, 256, 0, stream>>>(qt, gamma, beta, out);
}

// Round 2
// 172.290 us; speedup vs baseline: 1.0967x; 1.0967x over previous
//
#include <hip/hip_runtime.h>

// ============================================================================
// SelfAttentionLayer (RPE attention), MI355X bf16-MFMA implementation.
// Pipeline: cvt_all -> rpe_cvt -> gemm_proj(z=0..3: q,k,v,qt) -> pack_pm ->
//           attn (4-wave k-split, no-max exp2 softmax, in-LDS qrpe table,
//                 masked entries via sentinel table column) ->
//           gemm_wo (+qt residual, in-place) -> ln.
// ============================================================================

typedef short          bf16x8 __attribute__((ext_vector_type(8)));
typedef float          f32x4  __attribute__((ext_vector_type(4)));
typedef int            i32x4  __attribute__((ext_vector_type(4)));
typedef unsigned short u16x4  __attribute__((ext_vector_type(4)));
typedef unsigned short u16x8  __attribute__((ext_vector_type(8)));

#define SEQ 2048
#define EMB 1024
#define NH  16
#define HD  64
#define RL  512

#define MFMA16(a,b,c) __builtin_amdgcn_mfma_f32_16x16x32_bf16((a),(b),(c),0,0,0)

__device__ __forceinline__ unsigned short f2bf(float f){
  union{float f; unsigned u;} x; x.f=f;
  unsigned r = x.u + 0x7FFFu + ((x.u>>16)&1u);
  return (unsigned short)(r>>16);
}
__device__ __forceinline__ float bf2f(unsigned short u){
  union{unsigned u; float f;} x; x.u=((unsigned)u)<<16; return x.f;
}
__device__ __forceinline__ void gload16(const void* g, void* l){
  __builtin_amdgcn_global_load_lds((const __attribute__((address_space(1))) unsigned int*)g,
                                   (__attribute__((address_space(3))) unsigned int*)l, 16, 0, 0);
}
// 16B fragment read from a [rows][64]-bf16 LDS tile with per-8-row XOR swizzle.
__device__ __forceinline__ bf16x8 fragld(const unsigned short* t, int row, int chunk){
  int swz = chunk ^ (row & 7);
  return *(const bf16x8*)(t + row*64 + swz*8);
}

// ---------------------------------------------------------------------------
// f32 -> bf16 conversions
// ---------------------------------------------------------------------------
__global__ __launch_bounds__(256) void cvt_all(
    const float* __restrict__ s0, const float* __restrict__ s1, const float* __restrict__ s2,
    const float* __restrict__ s3, const float* __restrict__ s4, const float* __restrict__ s5,
    const float* __restrict__ s6, const float* __restrict__ s7,
    unsigned short* __restrict__ d0, unsigned short* __restrict__ d1, unsigned short* __restrict__ d2,
    unsigned short* __restrict__ d3, unsigned short* __restrict__ d4, unsigned short* __restrict__ d5,
    unsigned short* __restrict__ d6, unsigned short* __restrict__ d7)
{
  const float* s; unsigned short* d; int n;
  switch (blockIdx.y) {
    case 0: s=s0; d=d0; n=SEQ*EMB; break;
    case 1: s=s1; d=d1; n=SEQ*EMB; break;
    case 2: s=s2; d=d2; n=SEQ*EMB; break;
    case 3: s=s3; d=d3; n=EMB*EMB; break;
    case 4: s=s4; d=d4; n=EMB*EMB; break;
    case 5: s=s5; d=d5; n=EMB*EMB; break;
    case 6: s=s6; d=d6; n=EMB*EMB; break;
    default: s=s7; d=d7; n=EMB*EMB; break;
  }
  int i = (blockIdx.x*256 + threadIdx.x)*8;
  if (i >= n) return;
  f32x4 a = *(const f32x4*)(s+i);
  f32x4 b = *(const f32x4*)(s+i+4);
  u16x8 o;
  #pragma unroll
  for (int j=0;j<4;++j){ o[j]=f2bf(a[j]); o[4+j]=f2bf(b[j]); }
  *(u16x8*)(d+i) = o;
}

// rpe [l][h][d] f32 -> [h][l][d] bf16
__global__ __launch_bounds__(256) void rpe_cvt(const float* __restrict__ src,
                                               unsigned short* __restrict__ dst)
{
  int i = (blockIdx.x*256 + threadIdx.x)*4;
  int l = i >> 10;
  int h = (i >> 6) & 15;
  int d = i & 63;
  f32x4 a = *(const f32x4*)(src + i);
  u16x4 o;
  #pragma unroll
  for (int j=0;j<4;++j) o[j]=f2bf(a[j]);
  *(u16x4*)(dst + ((size_t)h*RL + l)*HD + d) = o;
}

// pm16[q][k] = mask>0.5 ? pos : 512   (sentinel col 512 holds -1e6 in table)
__global__ __launch_bounds__(256) void pack_pm(const int* __restrict__ pos,
                                               const float* __restrict__ mask,
                                               unsigned short* __restrict__ pm)
{
  int i = (blockIdx.x*256 + threadIdx.x)*4;
  i32x4 p = *(const i32x4*)(pos + i);
  f32x4 m = *(const f32x4*)(mask + i);
  u16x4 o;
  #pragma unroll
  for (int j=0;j<4;++j) o[j] = (m[j] > 0.5f) ? (unsigned short)p[j] : (unsigned short)512;
  *(u16x4*)(pm + i) = o;
}

// ---------------------------------------------------------------------------
// GEMM core: C[128x128] = A[M,1024] @ W[N,1024]^T  (bf16 in, f32 acc)
// ---------------------------------------------------------------------------
__device__ __forceinline__ void gemm_core(const unsigned short* __restrict__ A,
                                          const unsigned short* __restrict__ W,
                                          unsigned short* At, unsigned short* Wt,
                                          f32x4 acc[4][4], int m0, int n0)
{
  const int tid = threadIdx.x, lane = tid & 63, w = tid >> 6;
  const int rg = lane >> 3, sc = (lane & 7) ^ rg;
  const int c = lane & 15, g = lane >> 4;
  const int wm = w >> 1, wn = w & 1;

  for (int kt = 0; kt < EMB/64; ++kt) {
    __syncthreads();
    #pragma unroll
    for (int i = 0; i < 4; ++i) {
      int r = w*32 + i*8 + rg;
      gload16(A + (size_t)(m0+r)*EMB + kt*64 + sc*8, At + (w*32 + i*8)*64);
      gload16(W + (size_t)(n0+r)*EMB + kt*64 + sc*8, Wt + (w*32 + i*8)*64);
    }
    __syncthreads();
    #pragma unroll
    for (int kk = 0; kk < 2; ++kk) {
      bf16x8 af[4], bw[4];
      #pragma unroll
      for (int mf = 0; mf < 4; ++mf) af[mf] = fragld(At, wm*64 + mf*16 + c, kk*4 + g);
      #pragma unroll
      for (int nf = 0; nf < 4; ++nf) bw[nf] = fragld(Wt, wn*64 + nf*16 + c, kk*4 + g);
      #pragma unroll
      for (int mf = 0; mf < 4; ++mf)
        #pragma unroll
        for (int nf = 0; nf < 4; ++nf)
          acc[mf][nf] = MFMA16(af[mf], bw[nf], acc[mf][nf]);
    }
  }
}

// Fused projections. z: 0=Q(scaled by 2^-3 * log2e), 1=K, 2=V(transposed out), 3=QT(f32 out)
__global__ __launch_bounds__(256) void gemm_proj(
    const unsigned short* __restrict__ Aq, const unsigned short* __restrict__ Ak,
    const unsigned short* __restrict__ Av,
    const unsigned short* __restrict__ Wq, const unsigned short* __restrict__ Wk,
    const unsigned short* __restrict__ Wv, const unsigned short* __restrict__ Wqt,
    const float* __restrict__ bq, const float* __restrict__ bk,
    const float* __restrict__ bv, const float* __restrict__ bqt,
    unsigned short* __restrict__ q_out, unsigned short* __restrict__ k_out,
    unsigned short* __restrict__ vt_out, float* __restrict__ qt_out)
{
  __shared__ alignas(16) unsigned short At[128*64];
  __shared__ alignas(16) unsigned short Wt[128*64];
  const unsigned short *A, *W; const float* bias;
  const int z = blockIdx.z;
  if      (z == 0) { A=Aq; W=Wq;  bias=bq;  }
  else if (z == 1) { A=Ak; W=Wk;  bias=bk;  }
  else if (z == 2) { A=Av; W=Wv;  bias=bv;  }
  else             { A=Aq; W=Wqt; bias=bqt; }

  f32x4 acc[4][4];
  #pragma unroll
  for (int i=0;i<4;++i)
    #pragma unroll
    for (int j=0;j<4;++j) acc[i][j] = (f32x4){0.f,0.f,0.f,0.f};

  const int m0 = blockIdx.y*128, n0 = blockIdx.x*128;
  gemm_core(A, W, At, Wt, acc, m0, n0);

  const int lane = threadIdx.x & 63, w = threadIdx.x >> 6;
  const int c = lane & 15, g = lane >> 4, wm = w >> 1, wn = w & 1;
  const float QSCALE = 0.125f * 1.4426950408889634f;   // HDIM^-0.5 * log2(e)
  #pragma unroll
  for (int nf = 0; nf < 4; ++nf) {
    int n = n0 + wn*64 + nf*16 + c;
    float b = bias[n];
    #pragma unroll
    for (int mf = 0; mf < 4; ++mf) {
      int mb = m0 + wm*64 + mf*16 + g*4;
      if (z == 0) {
        #pragma unroll
        for (int j=0;j<4;++j) q_out[(size_t)(mb+j)*EMB + n] = f2bf((acc[mf][nf][j] + b)*QSCALE);
      } else if (z == 1) {
        #pragma unroll
        for (int j=0;j<4;++j) k_out[(size_t)(mb+j)*EMB + n] = f2bf(acc[mf][nf][j] + b);
      } else if (z == 2) {
        u16x4 pk;
        #pragma unroll
        for (int j=0;j<4;++j) pk[j] = f2bf(acc[mf][nf][j] + b);
        *(u16x4*)(vt_out + (size_t)n*SEQ + mb) = pk;     // V^T layout [n][s]
      } else {
        #pragma unroll
        for (int j=0;j<4;++j) qt_out[(size_t)(mb+j)*EMB + n] = acc[mf][nf][j] + b;
      }
    }
  }
}

// Output projection: qt[m][n] += att @ Wo^T + bo   (in-place residual)
__global__ __launch_bounds__(256) void gemm_wo(
    const unsigned short* __restrict__ A, const unsigned short* __restrict__ W,
    const float* __restrict__ bo, float* __restrict__ qt)
{
  __shared__ alignas(16) unsigned short At[128*64];
  __shared__ alignas(16) unsigned short Wt[128*64];
  f32x4 acc[4][4];
  #pragma unroll
  for (int i=0;i<4;++i)
    #pragma unroll
    for (int j=0;j<4;++j) acc[i][j] = (f32x4){0.f,0.f,0.f,0.f};
  const int m0 = blockIdx.y*128, n0 = blockIdx.x*128;
  gemm_core(A, W, At, Wt, acc, m0, n0);

  const int lane = threadIdx.x & 63, w = threadIdx.x >> 6;
  const int c = lane & 15, g = lane >> 4, wm = w >> 1, wn = w & 1;
  #pragma unroll
  for (int nf = 0; nf < 4; ++nf) {
    int n = n0 + wn*64 + nf*16 + c;
    float b = bo[n];
    #pragma unroll
    for (int mf = 0; mf < 4; ++mf) {
      int mb = m0 + wm*64 + mf*16 + g*4;
      #pragma unroll
      for (int j=0;j<4;++j) {
        size_t idx = (size_t)(mb+j)*EMB + n;
        qt[idx] = acc[mf][nf][j] + b + qt[idx];
      }
    }
  }
}

// ---------------------------------------------------------------------------
// Attention: block = (32 q-rows, 1 head), 4 waves (qh = w&1 selects 16 q-rows,
// ks = w>>1 selects 32-k half of the 64-k tile). Swapped QK^T (mfma(K,Q)),
// no-max exp2 softmax (log2e folded into Q), in-LDS qrpe table with sentinel
// column 512 = -1e6 for masked entries. Cross-pair (ks) reduce via LDS.
// ---------------------------------------------------------------------------
__global__ __launch_bounds__(256) void attn_kernel(
    const unsigned short* __restrict__ q_bf, const unsigned short* __restrict__ k_bf,
    const unsigned short* __restrict__ vt_bf, const unsigned short* __restrict__ rpe_bf,
    const unsigned short* __restrict__ pm, unsigned short* __restrict__ att_out)
{
  __shared__ alignas(16) unsigned short q_tile[32*64];     // swizzled
  __shared__ alignas(16) unsigned short k_tile[64*64];     // swizzled (also rpe chunks)
  __shared__ alignas(16) unsigned short vt_tile[64*64];    // swizzled, rows = d
  __shared__ alignas(16) unsigned short table[32*520];     // qrpe[q][l] + sentinel cols
  __shared__ alignas(16) unsigned short p_lds[4][16*40];   // per-wave P[q][k32]
  __shared__ float red[2][64][16];                         // ks-pair oacc reduce
  __shared__ float red2[2][16];                            // ks-pair sump reduce

  const int tid = threadIdx.x, lane = tid & 63, w = tid >> 6;
  const int qh = w & 1, ks = w >> 1;
  const int h = blockIdx.y;
  const int q0 = blockIdx.x * 32;
  const int rg = lane >> 3, sc = (lane & 7) ^ rg;
  const int c = lane & 15, g = lane >> 4;

  // stage Q tile (32 x 64): each wave 8 rows
  gload16(q_bf + (size_t)(q0 + w*8 + rg)*EMB + h*HD + sc*8, q_tile + (w*8)*64);
  __syncthreads();

  // prologue: table[q][l] = q_row . rpe_l  (wave w covers 16 l-rows per chunk)
  for (int ch = 0; ch < 8; ++ch) {
    __syncthreads();
    #pragma unroll
    for (int i = 0; i < 2; ++i)
      gload16(rpe_bf + ((size_t)h*RL + ch*64 + w*16 + i*8 + rg)*HD + sc*8,
              k_tile + (w*16 + i*8)*64);
    __syncthreads();
    #pragma unroll
    for (int qq = 0; qq < 2; ++qq) {
      f32x4 dd = (f32x4){0.f,0.f,0.f,0.f};
      dd = MFMA16(fragld(k_tile, w*16 + c, g),     fragld(q_tile, qq*16 + c, g),     dd);
      dd = MFMA16(fragld(k_tile, w*16 + c, 4 + g), fragld(q_tile, qq*16 + c, 4 + g), dd);
      u16x4 pk;
      #pragma unroll
      for (int j = 0; j < 4; ++j) pk[j] = f2bf(dd[j]);
      *(u16x4*)(table + (qq*16 + c)*520 + ch*64 + w*16 + g*4) = pk;
    }
  }
  // sentinel columns 512..519 = bf16(-1e6): masked-out gather target
  table[(tid >> 3)*520 + 512 + (tid & 7)] = 0xC974;

  f32x4 oacc[4];
  #pragma unroll
  for (int i=0;i<4;++i) oacc[i] = (f32x4){0.f,0.f,0.f,0.f};
  float sump = 0.f;
  const bf16x8 qf0 = fragld(q_tile, qh*16 + c, g);
  const bf16x8 qf1 = fragld(q_tile, qh*16 + c, 4 + g);
  unsigned short* pw = p_lds[w];
  const unsigned short* trow = table + (qh*16 + c)*520;
  const size_t qg = (size_t)(q0 + qh*16 + c)*SEQ;

  for (int kt = 0; kt < SEQ/64; ++kt) {
    const int kb = kt*64;
    __syncthreads();
    #pragma unroll
    for (int i = 0; i < 2; ++i) {
      gload16(k_bf  + (size_t)(kb + w*16 + i*8 + rg)*EMB + h*HD + sc*8, k_tile  + (w*16 + i*8)*64);
      gload16(vt_bf + ((size_t)h*HD + w*16 + i*8 + rg)*SEQ + kb + sc*8, vt_tile + (w*16 + i*8)*64);
    }
    // pm loads for this tile — overlap the staging drain (T14)
    u16x4 pv0 = *(const u16x4*)(pm + qg + kb + ks*32 + g*4);
    u16x4 pv1 = *(const u16x4*)(pm + qg + kb + ks*32 + 16 + g*4);
    __syncthreads();

    #pragma unroll
    for (int kf = 0; kf < 2; ++kf) {
      f32x4 sf = (f32x4){0.f,0.f,0.f,0.f};
      sf = MFMA16(fragld(k_tile, ks*32 + kf*16 + c, g),     qf0, sf);
      sf = MFMA16(fragld(k_tile, ks*32 + kf*16 + c, 4 + g), qf1, sf);
      u16x4 pv = kf ? pv1 : pv0;
      u16x4 pk;
      #pragma unroll
      for (int j = 0; j < 4; ++j) {
        float rv = bf2f(trow[pv[j]]);
        float p  = exp2f(sf[j] + rv);
        sump += p;
        pk[j] = f2bf(p);
      }
      *(u16x4*)(pw + c*40 + kf*16 + g*4) = pk;
    }
    // same-wave LDS RAW: writes complete before fragment read
    asm volatile("s_waitcnt lgkmcnt(0)" ::: "memory");
    bf16x8 pa = *(const bf16x8*)(pw + c*40 + g*8);
    #pragma unroll
    for (int df = 0; df < 4; ++df)
      oacc[df] = MFMA16(pa, fragld(vt_tile, df*16 + c, ks*4 + g), oacc[df]);
  }

  // per-q sum within wave (lane c holds q = qh*16+c partials across g)
  sump += __shfl_xor(sump, 16);
  sump += __shfl_xor(sump, 32);

  if (ks) {
    #pragma unroll
    for (int df = 0; df < 4; ++df)
      *(f32x4*)(&red[qh][lane][df*4]) = oacc[df];
    if (g == 0) red2[qh][c] = sump;
  }
  __syncthreads();
  if (!ks) {
    sump += red2[qh][c];
    #pragma unroll
    for (int df = 0; df < 4; ++df)
      oacc[df] += *(const f32x4*)(&red[qh][lane][df*4]);
    #pragma unroll
    for (int j = 0; j < 4; ++j) {
      float inv = 1.0f / __shfl(sump, g*4 + j);
      int qrow = q0 + qh*16 + g*4 + j;
      #pragma unroll
      for (int df = 0; df < 4; ++df)
        att_out[(size_t)qrow*EMB + h*HD + df*16 + c] = f2bf(oacc[df][j] * inv);
    }
  }
}

// ---------------------------------------------------------------------------
// LayerNorm over rows of qt (f32), gamma/beta, -> d_out
// ---------------------------------------------------------------------------
__global__ __launch_bounds__(256) void ln_kernel(const float* __restrict__ x,
                                                 const float* __restrict__ gamma,
                                                 const float* __restrict__ beta,
                                                 float* __restrict__ out)
{
  const int row = blockIdx.x, t = threadIdx.x;
  f32x4 v = *(const f32x4*)(x + (size_t)row*EMB + t*4);
  float s = v[0]+v[1]+v[2]+v[3];
  #pragma unroll
  for (int o = 32; o > 0; o >>= 1) s += __shfl_xor(s, o);
  __shared__ float r1[4], r2[4];
  if ((t & 63) == 0) r1[t >> 6] = s;
  __syncthreads();
  float mean = (r1[0]+r1[1]+r1[2]+r1[3]) * (1.0f/EMB);
  f32x4 d; float q = 0.f;
  #pragma unroll
  for (int j=0;j<4;++j){ d[j] = v[j] - mean; q += d[j]*d[j]; }
  #pragma unroll
  for (int o = 32; o > 0; o >>= 1) q += __shfl_xor(q, o);
  if ((t & 63) == 0) r2[t >> 6] = q;
  __syncthreads();
  float var = (r2[0]+r2[1]+r2[2]+r2[3]) * (1.0f/EMB);
  float rs = rsqrtf(var + 1e-6f);
  f32x4 gg = *(const f32x4*)(gamma + t*4);
  f32x4 bb = *(const f32x4*)(beta  + t*4);
  f32x4 o4;
  #pragma unroll
  for (int j=0;j<4;++j) o4[j] = d[j]*rs*gg[j] + bb[j];
  *(f32x4*)(out + (size_t)row*EMB + t*4) = o4;
}

// ---------------------------------------------------------------------------
extern "C" void kernel_launch(void* const* d_in, const int* in_sizes, int n_in,
                              void* d_out, int out_size, void* d_ws, size_t ws_size,
                              hipStream_t stream)
{
  (void)in_sizes; (void)n_in; (void)out_size;
  const float* query = (const float*)d_in[0];
  const float* key   = (const float*)d_in[1];
  const float* value = (const float*)d_in[2];
  const int*   pos   = (const int*)  d_in[3];
  const float* mask  = (const float*)d_in[4];
  const float* Wq    = (const float*)d_in[5];
  const float* bq    = (const float*)d_in[6];
  const float* Wk    = (const float*)d_in[7];
  const float* bk    = (const float*)d_in[8];
  const float* Wv    = (const float*)d_in[9];
  const float* bv    = (const float*)d_in[10];
  const float* rpe   = (const float*)d_in[11];
  const float* Wqt   = (const float*)d_in[12];
  const float* bqt   = (const float*)d_in[13];
  const float* Wo    = (const float*)d_in[14];
  const float* bo    = (const float*)d_in[15];
  const float* gamma = (const float*)d_in[16];
  const float* beta  = (const float*)d_in[17];
  float* out = (float*)d_out;

  // workspace layout (bytes)
  char* ws = (char*)d_ws;
  const size_t OFF_QBF   = 0;          // q (scaled)   [2048][1024] bf16  4MB
  const size_t OFF_KBF   = 4194304;    // k            [2048][1024] bf16  4MB
  const size_t OFF_VTBF  = 8388608;    // v^T          [1024][2048] bf16  4MB
  const size_t OFF_QRYBF = 12582912;   // query bf16 4MB (later aliased by pm16)
  const size_t OFF_KEYBF = 16777216;   // key bf16   4MB (later aliased by pm16)
  const size_t OFF_VALBF = 20971520;   // value bf16   4MB
  const size_t OFF_WQ    = 25165824;   // 2MB each
  const size_t OFF_WK    = 27262976;
  const size_t OFF_WV    = 29360128;
  const size_t OFF_WQT   = 31457280;
  const size_t OFF_WO    = 33554432;
  const size_t OFF_RPE   = 35651584;   // [16][512][64] bf16  1MB
  const size_t OFF_QT    = 36700160;   // qt / pre-LN  [2048][1024] f32  8MB
  const size_t OFF_ATT   = 45088768;   // attention out bf16  4MB
  const size_t WS_NEED   = 49283072;
  if (ws_size < WS_NEED) return;  // visible failure instead of OOB writes

  unsigned short* q_bf   = (unsigned short*)(ws + OFF_QBF);
  unsigned short* k_bf   = (unsigned short*)(ws + OFF_KBF);
  unsigned short* vt_bf  = (unsigned short*)(ws + OFF_VTBF);
  unsigned short* qry_bf = (unsigned short*)(ws + OFF_QRYBF);
  unsigned short* key_bf = (unsigned short*)(ws + OFF_KEYBF);
  unsigned short* val_bf = (unsigned short*)(ws + OFF_VALBF);
  unsigned short* wq_bf  = (unsigned short*)(ws + OFF_WQ);
  unsigned short* wk_bf  = (unsigned short*)(ws + OFF_WK);
  unsigned short* wv_bf  = (unsigned short*)(ws + OFF_WV);
  unsigned short* wqt_bf = (unsigned short*)(ws + OFF_WQT);
  unsigned short* wo_bf  = (unsigned short*)(ws + OFF_WO);
  unsigned short* rpe_bf = (unsigned short*)(ws + OFF_RPE);
  float*          qt     = (float*)         (ws + OFF_QT);
  unsigned short* att_bf = (unsigned short*)(ws + OFF_ATT);
  unsigned short* pm16   = (unsigned short*)(ws + OFF_QRYBF);  // 8MB alias, safe after gemm_proj

  cvt_all<<<dim3(1024, 8), 256, 0, stream>>>(
      query, key, value, Wq, Wk, Wv, Wqt, Wo,
      qry_bf, key_bf, val_bf, wq_bf, wk_bf, wv_bf, wqt_bf, wo_bf);
  rpe_cvt<<<512, 256, 0, stream>>>(rpe, rpe_bf);
  gemm_proj<<<dim3(8, 16, 4), 256, 0, stream>>>(
      qry_bf, key_bf, val_bf, wq_bf, wk_bf, wv_bf, wqt_bf,
      bq, bk, bv, bqt, q_bf, k_bf, vt_bf, qt);
  pack_pm<<<SEQ*SEQ/1024, 256, 0, stream>>>(pos, mask, pm16);
  attn_kernel<<<dim3(SEQ/32, NH), 256, 0, stream>>>(
      q_bf, k_bf, vt_bf, rpe_bf, pm16, att_bf);
  gemm_wo<<<dim3(8, 16), 256, 0, stream>>>(att_bf, wo_bf, bo, qt);
  ln_kernel<<<2048, 256, 0, stream>>>(qt, gamma, beta, out);
}

// Round 3
// 146.347 us; speedup vs baseline: 1.2911x; 1.1773x over previous
//
#include <hip/hip_runtime.h>

// ============================================================================
// SelfAttentionLayer (RPE attention), MI355X bf16-MFMA implementation.
// Pipeline: cvt_all -> rpe_cvt -> gemm_proj(z=0..3: q,k,v,qt) -> pack_pm ->
//           attn (4-wave k-split, no-max exp2 softmax, in-LDS fp8(e5m2) qrpe
//                 table, masked entries via sentinel -inf column, LDS pool
//                 aliasing -> 38KB -> 4 blocks/CU) ->
//           gemm_wo (+qt residual, in-place) -> ln.
// ============================================================================

typedef short          bf16x8 __attribute__((ext_vector_type(8)));
typedef float          f32x4  __attribute__((ext_vector_type(4)));
typedef int            i32x4  __attribute__((ext_vector_type(4)));
typedef unsigned short u16x4  __attribute__((ext_vector_type(4)));
typedef unsigned short u16x8  __attribute__((ext_vector_type(8)));

#define SEQ 2048
#define EMB 1024
#define NH  16
#define HD  64
#define RL  512

#define MFMA16(a,b,c) __builtin_amdgcn_mfma_f32_16x16x32_bf16((a),(b),(c),0,0,0)

__device__ __forceinline__ unsigned short f2bf(float f){
  union{float f; unsigned u;} x; x.f=f;
  unsigned r = x.u + 0x7FFFu + ((x.u>>16)&1u);
  return (unsigned short)(r>>16);
}
__device__ __forceinline__ float bf2f(unsigned short u){
  union{unsigned u; float f;} x; x.u=((unsigned)u)<<16; return x.f;
}
// f32 -> e5m2 (RTNE via f16 then round-truncate top byte). Values are tiny, no overflow.
__device__ __forceinline__ unsigned char f2e5(float f){
  union{_Float16 h; unsigned short u;} cv; cv.h = (_Float16)f;
  unsigned short b = cv.u;
  unsigned r = (unsigned)b + 0x7Fu + ((b>>8)&1u);
  return (unsigned char)(r>>8);
}
// e5m2 -> f32: byte<<8 is a valid fp16
__device__ __forceinline__ float e52f(unsigned char b){
  union{unsigned short u; _Float16 h;} cv; cv.u = ((unsigned short)b)<<8;
  return (float)cv.h;
}
__device__ __forceinline__ void gload16(const void* g, void* l){
  __builtin_amdgcn_global_load_lds((const __attribute__((address_space(1))) unsigned int*)g,
                                   (__attribute__((address_space(3))) unsigned int*)l, 16, 0, 0);
}
// 16B fragment read from a [rows][64]-bf16 LDS tile with per-8-row XOR swizzle.
__device__ __forceinline__ bf16x8 fragld(const unsigned short* t, int row, int chunk){
  int swz = chunk ^ (row & 7);
  return *(const bf16x8*)(t + row*64 + swz*8);
}

// ---------------------------------------------------------------------------
// f32 -> bf16 conversions
// ---------------------------------------------------------------------------
__global__ __launch_bounds__(256) void cvt_all(
    const float* __restrict__ s0, const float* __restrict__ s1, const float* __restrict__ s2,
    const float* __restrict__ s3, const float* __restrict__ s4, const float* __restrict__ s5,
    const float* __restrict__ s6, const float* __restrict__ s7,
    unsigned short* __restrict__ d0, unsigned short* __restrict__ d1, unsigned short* __restrict__ d2,
    unsigned short* __restrict__ d3, unsigned short* __restrict__ d4, unsigned short* __restrict__ d5,
    unsigned short* __restrict__ d6, unsigned short* __restrict__ d7)
{
  const float* s; unsigned short* d; int n;
  switch (blockIdx.y) {
    case 0: s=s0; d=d0; n=SEQ*EMB; break;
    case 1: s=s1; d=d1; n=SEQ*EMB; break;
    case 2: s=s2; d=d2; n=SEQ*EMB; break;
    case 3: s=s3; d=d3; n=EMB*EMB; break;
    case 4: s=s4; d=d4; n=EMB*EMB; break;
    case 5: s=s5; d=d5; n=EMB*EMB; break;
    case 6: s=s6; d=d6; n=EMB*EMB; break;
    default: s=s7; d=d7; n=EMB*EMB; break;
  }
  int i = (blockIdx.x*256 + threadIdx.x)*8;
  if (i >= n) return;
  f32x4 a = *(const f32x4*)(s+i);
  f32x4 b = *(const f32x4*)(s+i+4);
  u16x8 o;
  #pragma unroll
  for (int j=0;j<4;++j){ o[j]=f2bf(a[j]); o[4+j]=f2bf(b[j]); }
  *(u16x8*)(d+i) = o;
}

// rpe [l][h][d] f32 -> [h][l][d] bf16
__global__ __launch_bounds__(256) void rpe_cvt(const float* __restrict__ src,
                                               unsigned short* __restrict__ dst)
{
  int i = (blockIdx.x*256 + threadIdx.x)*4;
  int l = i >> 10;
  int h = (i >> 6) & 15;
  int d = i & 63;
  f32x4 a = *(const f32x4*)(src + i);
  u16x4 o;
  #pragma unroll
  for (int j=0;j<4;++j) o[j]=f2bf(a[j]);
  *(u16x4*)(dst + ((size_t)h*RL + l)*HD + d) = o;
}

// pm16[q][k] = mask>0.5 ? pos : 512   (sentinel col 512 holds -inf in table)
__global__ __launch_bounds__(256) void pack_pm(const int* __restrict__ pos,
                                               const float* __restrict__ mask,
                                               unsigned short* __restrict__ pm)
{
  int i = (blockIdx.x*256 + threadIdx.x)*4;
  i32x4 p = *(const i32x4*)(pos + i);
  f32x4 m = *(const f32x4*)(mask + i);
  u16x4 o;
  #pragma unroll
  for (int j=0;j<4;++j) o[j] = (m[j] > 0.5f) ? (unsigned short)p[j] : (unsigned short)512;
  *(u16x4*)(pm + i) = o;
}

// ---------------------------------------------------------------------------
// GEMM core: C[128x128] = A[M,1024] @ W[N,1024]^T  (bf16 in, f32 acc)
// ---------------------------------------------------------------------------
__device__ __forceinline__ void gemm_core(const unsigned short* __restrict__ A,
                                          const unsigned short* __restrict__ W,
                                          unsigned short* At, unsigned short* Wt,
                                          f32x4 acc[4][4], int m0, int n0)
{
  const int tid = threadIdx.x, lane = tid & 63, w = tid >> 6;
  const int rg = lane >> 3, sc = (lane & 7) ^ rg;
  const int c = lane & 15, g = lane >> 4;
  const int wm = w >> 1, wn = w & 1;

  for (int kt = 0; kt < EMB/64; ++kt) {
    __syncthreads();
    #pragma unroll
    for (int i = 0; i < 4; ++i) {
      int r = w*32 + i*8 + rg;
      gload16(A + (size_t)(m0+r)*EMB + kt*64 + sc*8, At + (w*32 + i*8)*64);
      gload16(W + (size_t)(n0+r)*EMB + kt*64 + sc*8, Wt + (w*32 + i*8)*64);
    }
    __syncthreads();
    #pragma unroll
    for (int kk = 0; kk < 2; ++kk) {
      bf16x8 af[4], bw[4];
      #pragma unroll
      for (int mf = 0; mf < 4; ++mf) af[mf] = fragld(At, wm*64 + mf*16 + c, kk*4 + g);
      #pragma unroll
      for (int nf = 0; nf < 4; ++nf) bw[nf] = fragld(Wt, wn*64 + nf*16 + c, kk*4 + g);
      #pragma unroll
      for (int mf = 0; mf < 4; ++mf)
        #pragma unroll
        for (int nf = 0; nf < 4; ++nf)
          acc[mf][nf] = MFMA16(af[mf], bw[nf], acc[mf][nf]);
    }
  }
}

// Fused projections. z: 0=Q(scaled by 2^-3 * log2e), 1=K, 2=V(transposed out), 3=QT(f32 out)
__global__ __launch_bounds__(256) void gemm_proj(
    const unsigned short* __restrict__ Aq, const unsigned short* __restrict__ Ak,
    const unsigned short* __restrict__ Av,
    const unsigned short* __restrict__ Wq, const unsigned short* __restrict__ Wk,
    const unsigned short* __restrict__ Wv, const unsigned short* __restrict__ Wqt,
    const float* __restrict__ bq, const float* __restrict__ bk,
    const float* __restrict__ bv, const float* __restrict__ bqt,
    unsigned short* __restrict__ q_out, unsigned short* __restrict__ k_out,
    unsigned short* __restrict__ vt_out, float* __restrict__ qt_out)
{
  __shared__ alignas(16) unsigned short At[128*64];
  __shared__ alignas(16) unsigned short Wt[128*64];
  const unsigned short *A, *W; const float* bias;
  const int z = blockIdx.z;
  if      (z == 0) { A=Aq; W=Wq;  bias=bq;  }
  else if (z == 1) { A=Ak; W=Wk;  bias=bk;  }
  else if (z == 2) { A=Av; W=Wv;  bias=bv;  }
  else             { A=Aq; W=Wqt; bias=bqt; }

  f32x4 acc[4][4];
  #pragma unroll
  for (int i=0;i<4;++i)
    #pragma unroll
    for (int j=0;j<4;++j) acc[i][j] = (f32x4){0.f,0.f,0.f,0.f};

  const int m0 = blockIdx.y*128, n0 = blockIdx.x*128;
  gemm_core(A, W, At, Wt, acc, m0, n0);

  const int lane = threadIdx.x & 63, w = threadIdx.x >> 6;
  const int c = lane & 15, g = lane >> 4, wm = w >> 1, wn = w & 1;
  const float QSCALE = 0.125f * 1.4426950408889634f;   // HDIM^-0.5 * log2(e)
  #pragma unroll
  for (int nf = 0; nf < 4; ++nf) {
    int n = n0 + wn*64 + nf*16 + c;
    float b = bias[n];
    #pragma unroll
    for (int mf = 0; mf < 4; ++mf) {
      int mb = m0 + wm*64 + mf*16 + g*4;
      if (z == 0) {
        #pragma unroll
        for (int j=0;j<4;++j) q_out[(size_t)(mb+j)*EMB + n] = f2bf((acc[mf][nf][j] + b)*QSCALE);
      } else if (z == 1) {
        #pragma unroll
        for (int j=0;j<4;++j) k_out[(size_t)(mb+j)*EMB + n] = f2bf(acc[mf][nf][j] + b);
      } else if (z == 2) {
        u16x4 pk;
        #pragma unroll
        for (int j=0;j<4;++j) pk[j] = f2bf(acc[mf][nf][j] + b);
        *(u16x4*)(vt_out + (size_t)n*SEQ + mb) = pk;     // V^T layout [n][s]
      } else {
        #pragma unroll
        for (int j=0;j<4;++j) qt_out[(size_t)(mb+j)*EMB + n] = acc[mf][nf][j] + b;
      }
    }
  }
}

// Output projection: qt[m][n] += att @ Wo^T + bo   (in-place residual)
__global__ __launch_bounds__(256) void gemm_wo(
    const unsigned short* __restrict__ A, const unsigned short* __restrict__ W,
    const float* __restrict__ bo, float* __restrict__ qt)
{
  __shared__ alignas(16) unsigned short At[128*64];
  __shared__ alignas(16) unsigned short Wt[128*64];
  f32x4 acc[4][4];
  #pragma unroll
  for (int i=0;i<4;++i)
    #pragma unroll
    for (int j=0;j<4;++j) acc[i][j] = (f32x4){0.f,0.f,0.f,0.f};
  const int m0 = blockIdx.y*128, n0 = blockIdx.x*128;
  gemm_core(A, W, At, Wt, acc, m0, n0);

  const int lane = threadIdx.x & 63, w = threadIdx.x >> 6;
  const int c = lane & 15, g = lane >> 4, wm = w >> 1, wn = w & 1;
  #pragma unroll
  for (int nf = 0; nf < 4; ++nf) {
    int n = n0 + wn*64 + nf*16 + c;
    float b = bo[n];
    #pragma unroll
    for (int mf = 0; mf < 4; ++mf) {
      int mb = m0 + wm*64 + mf*16 + g*4;
      #pragma unroll
      for (int j=0;j<4;++j) {
        size_t idx = (size_t)(mb+j)*EMB + n;
        qt[idx] = acc[mf][nf][j] + b + qt[idx];
      }
    }
  }
}

// ---------------------------------------------------------------------------
// Attention: block = (32 q-rows, 1 head), 4 waves (qh = w&1 -> 16 q-rows,
// ks = w>>1 -> 32-k half of the 64-k tile). Swapped QK^T (mfma(K,Q)),
// no-max exp2 softmax (log2e folded into Q), in-LDS e5m2 qrpe table with
// sentinel col 512 = -inf. LDS pool aliased: 38.1KB -> 4 blocks/CU.
// ---------------------------------------------------------------------------
__global__ __launch_bounds__(256) void attn_kernel(
    const unsigned short* __restrict__ q_bf, const unsigned short* __restrict__ k_bf,
    const unsigned short* __restrict__ vt_bf, const unsigned short* __restrict__ rpe_bf,
    const unsigned short* __restrict__ pm, unsigned short* __restrict__ att_out)
{
  // pool carve (38144 B):
  //  [0,8192)      k_tile  (64x64 bf16, swizzled)      | red (post-loop alias)
  //  [8192,16384)  vt_tile (64x64 bf16, swizzled)
  //  [16384,33024) table8  (32 x 520 e5m2)
  //  [33024,38144) q_tile 4KB (prologue) | p_lds 4x640 u16 (loop) | red2 (post)
  __shared__ alignas(16) unsigned char pool[38144];
  unsigned short* k_tile  = (unsigned short*)(pool);
  unsigned short* vt_tile = (unsigned short*)(pool + 8192);
  unsigned char*  table8  = pool + 16384;
  unsigned short* q_tile  = (unsigned short*)(pool + 33024);
  unsigned short* p_base  = (unsigned short*)(pool + 33024);
  float*          red     = (float*)(pool);            // [2][64][16]
  float*          red2    = (float*)(pool + 33024);    // [2][16]

  const int tid = threadIdx.x, lane = tid & 63, w = tid >> 6;
  const int qh = w & 1, ks = w >> 1;
  const int h = blockIdx.y;
  const int q0 = blockIdx.x * 32;
  const int rg = lane >> 3, sc = (lane & 7) ^ rg;
  const int c = lane & 15, g = lane >> 4;

  // stage Q tile (32 x 64): each wave 8 rows
  gload16(q_bf + (size_t)(q0 + w*8 + rg)*EMB + h*HD + sc*8, q_tile + (w*8)*64);
  __syncthreads();

  // prologue: table[q][l] = q_row . rpe_l  (wave w covers 16 l-rows per chunk)
  for (int ch = 0; ch < 8; ++ch) {
    __syncthreads();
    #pragma unroll
    for (int i = 0; i < 2; ++i)
      gload16(rpe_bf + ((size_t)h*RL + ch*64 + w*16 + i*8 + rg)*HD + sc*8,
              k_tile + (w*16 + i*8)*64);
    __syncthreads();
    #pragma unroll
    for (int qq = 0; qq < 2; ++qq) {
      f32x4 dd = (f32x4){0.f,0.f,0.f,0.f};
      dd = MFMA16(fragld(k_tile, w*16 + c, g),     fragld(q_tile, qq*16 + c, g),     dd);
      dd = MFMA16(fragld(k_tile, w*16 + c, 4 + g), fragld(q_tile, qq*16 + c, 4 + g), dd);
      unsigned pk = (unsigned)f2e5(dd[0]) | ((unsigned)f2e5(dd[1])<<8)
                  | ((unsigned)f2e5(dd[2])<<16) | ((unsigned)f2e5(dd[3])<<24);
      *(unsigned*)(table8 + (qq*16 + c)*520 + ch*64 + w*16 + g*4) = pk;
    }
  }
  // sentinel col 512 = e5m2 -inf (0xFC): masked-out gather target
  if (tid < 32) table8[tid*520 + 512] = 0xFC;

  f32x4 oacc[4];
  #pragma unroll
  for (int i=0;i<4;++i) oacc[i] = (f32x4){0.f,0.f,0.f,0.f};
  float sump = 0.f;
  const bf16x8 qf0 = fragld(q_tile, qh*16 + c, g);
  const bf16x8 qf1 = fragld(q_tile, qh*16 + c, 4 + g);
  unsigned short* pw = p_base + w*640;
  const unsigned char* trow = table8 + (qh*16 + c)*520;
  const size_t qg = (size_t)(q0 + qh*16 + c)*SEQ;

  for (int kt = 0; kt < SEQ/64; ++kt) {
    const int kb = kt*64;
    __syncthreads();   // also orders prologue q_tile reads before p_lds alias writes
    #pragma unroll
    for (int i = 0; i < 2; ++i) {
      gload16(k_bf  + (size_t)(kb + w*16 + i*8 + rg)*EMB + h*HD + sc*8, k_tile  + (w*16 + i*8)*64);
      gload16(vt_bf + ((size_t)h*HD + w*16 + i*8 + rg)*SEQ + kb + sc*8, vt_tile + (w*16 + i*8)*64);
    }
    // pm loads for this tile — overlap the staging drain (T14)
    u16x4 pv0 = *(const u16x4*)(pm + qg + kb + ks*32 + g*4);
    u16x4 pv1 = *(const u16x4*)(pm + qg + kb + ks*32 + 16 + g*4);
    __syncthreads();

    #pragma unroll
    for (int kf = 0; kf < 2; ++kf) {
      f32x4 sf = (f32x4){0.f,0.f,0.f,0.f};
      sf = MFMA16(fragld(k_tile, ks*32 + kf*16 + c, g),     qf0, sf);
      sf = MFMA16(fragld(k_tile, ks*32 + kf*16 + c, 4 + g), qf1, sf);
      u16x4 pv = kf ? pv1 : pv0;
      u16x4 pk;
      #pragma unroll
      for (int j = 0; j < 4; ++j) {
        float rv = e52f(trow[pv[j]]);
        float p  = exp2f(sf[j] + rv);
        sump += p;
        pk[j] = f2bf(p);
      }
      *(u16x4*)(pw + c*40 + kf*16 + g*4) = pk;
    }
    // same-wave LDS RAW: writes complete before fragment read
    asm volatile("s_waitcnt lgkmcnt(0)" ::: "memory");
    bf16x8 pa = *(const bf16x8*)(pw + c*40 + g*8);
    #pragma unroll
    for (int df = 0; df < 4; ++df)
      oacc[df] = MFMA16(pa, fragld(vt_tile, df*16 + c, ks*4 + g), oacc[df]);
  }

  // per-q sum within wave (lane c holds q = qh*16+c partials across g)
  sump += __shfl_xor(sump, 16);
  sump += __shfl_xor(sump, 32);

  __syncthreads();   // all waves done with k_tile/vt_tile/p_lds before alias reuse
  if (ks) {
    #pragma unroll
    for (int df = 0; df < 4; ++df)
      *(f32x4*)(&red[(qh*64 + lane)*16 + df*4]) = oacc[df];
    if (g == 0) red2[qh*16 + c] = sump;
  }
  __syncthreads();
  if (!ks) {
    sump += red2[qh*16 + c];
    #pragma unroll
    for (int df = 0; df < 4; ++df)
      oacc[df] += *(const f32x4*)(&red[(qh*64 + lane)*16 + df*4]);
    #pragma unroll
    for (int j = 0; j < 4; ++j) {
      float inv = 1.0f / __shfl(sump, g*4 + j);
      int qrow = q0 + qh*16 + g*4 + j;
      #pragma unroll
      for (int df = 0; df < 4; ++df)
        att_out[(size_t)qrow*EMB + h*HD + df*16 + c] = f2bf(oacc[df][j] * inv);
    }
  }
}

// ---------------------------------------------------------------------------
// LayerNorm over rows of qt (f32), gamma/beta, -> d_out
// ---------------------------------------------------------------------------
__global__ __launch_bounds__(256) void ln_kernel(const float* __restrict__ x,
                                                 const float* __restrict__ gamma,
                                                 const float* __restrict__ beta,
                                                 float* __restrict__ out)
{
  const int row = blockIdx.x, t = threadIdx.x;
  f32x4 v = *(const f32x4*)(x + (size_t)row*EMB + t*4);
  float s = v[0]+v[1]+v[2]+v[3];
  #pragma unroll
  for (int o = 32; o > 0; o >>= 1) s += __shfl_xor(s, o);
  __shared__ float r1[4], r2[4];
  if ((t & 63) == 0) r1[t >> 6] = s;
  __syncthreads();
  float mean = (r1[0]+r1[1]+r1[2]+r1[3]) * (1.0f/EMB);
  f32x4 d; float q = 0.f;
  #pragma unroll
  for (int j=0;j<4;++j){ d[j] = v[j] - mean; q += d[j]*d[j]; }
  #pragma unroll
  for (int o = 32; o > 0; o >>= 1) q += __shfl_xor(q, o);
  if ((t & 63) == 0) r2[t >> 6] = q;
  __syncthreads();
  float var = (r2[0]+r2[1]+r2[2]+r2[3]) * (1.0f/EMB);
  float rs = rsqrtf(var + 1e-6f);
  f32x4 gg = *(const f32x4*)(gamma + t*4);
  f32x4 bb = *(const f32x4*)(beta  + t*4);
  f32x4 o4;
  #pragma unroll
  for (int j=0;j<4;++j) o4[j] = d[j]*rs*gg[j] + bb[j];
  *(f32x4*)(out + (size_t)row*EMB + t*4) = o4;
}

// ---------------------------------------------------------------------------
extern "C" void kernel_launch(void* const* d_in, const int* in_sizes, int n_in,
                              void* d_out, int out_size, void* d_ws, size_t ws_size,
                              hipStream_t stream)
{
  (void)in_sizes; (void)n_in; (void)out_size;
  const float* query = (const float*)d_in[0];
  const float* key   = (const float*)d_in[1];
  const float* value = (const float*)d_in[2];
  const int*   pos   = (const int*)  d_in[3];
  const float* mask  = (const float*)d_in[4];
  const float* Wq    = (const float*)d_in[5];
  const float* bq    = (const float*)d_in[6];
  const float* Wk    = (const float*)d_in[7];
  const float* bk    = (const float*)d_in[8];
  const float* Wv    = (const float*)d_in[9];
  const float* bv    = (const float*)d_in[10];
  const float* rpe   = (const float*)d_in[11];
  const float* Wqt   = (const float*)d_in[12];
  const float* bqt   = (const float*)d_in[13];
  const float* Wo    = (const float*)d_in[14];
  const float* bo    = (const float*)d_in[15];
  const float* gamma = (const float*)d_in[16];
  const float* beta  = (const float*)d_in[17];
  float* out = (float*)d_out;

  // workspace layout (bytes)
  char* ws = (char*)d_ws;
  const size_t OFF_QBF   = 0;          // q (scaled)   [2048][1024] bf16  4MB
  const size_t OFF_KBF   = 4194304;    // k            [2048][1024] bf16  4MB
  const size_t OFF_VTBF  = 8388608;    // v^T          [1024][2048] bf16  4MB
  const size_t OFF_QRYBF = 12582912;   // query bf16 4MB (later aliased by pm16)
  const size_t OFF_KEYBF = 16777216;   // key bf16   4MB (later aliased by pm16)
  const size_t OFF_VALBF = 20971520;   // value bf16   4MB
  const size_t OFF_WQ    = 25165824;   // 2MB each
  const size_t OFF_WK    = 27262976;
  const size_t OFF_WV    = 29360128;
  const size_t OFF_WQT   = 31457280;
  const size_t OFF_WO    = 33554432;
  const size_t OFF_RPE   = 35651584;   // [16][512][64] bf16  1MB
  const size_t OFF_QT    = 36700160;   // qt / pre-LN  [2048][1024] f32  8MB
  const size_t OFF_ATT   = 45088768;   // attention out bf16  4MB
  const size_t WS_NEED   = 49283072;
  if (ws_size < WS_NEED) return;  // visible failure instead of OOB writes

  unsigned short* q_bf   = (unsigned short*)(ws + OFF_QBF);
  unsigned short* k_bf   = (unsigned short*)(ws + OFF_KBF);
  unsigned short* vt_bf  = (unsigned short*)(ws + OFF_VTBF);
  unsigned short* qry_bf = (unsigned short*)(ws + OFF_QRYBF);
  unsigned short* key_bf = (unsigned short*)(ws + OFF_KEYBF);
  unsigned short* val_bf = (unsigned short*)(ws + OFF_VALBF);
  unsigned short* wq_bf  = (unsigned short*)(ws + OFF_WQ);
  unsigned short* wk_bf  = (unsigned short*)(ws + OFF_WK);
  unsigned short* wv_bf  = (unsigned short*)(ws + OFF_WV);
  unsigned short* wqt_bf = (unsigned short*)(ws + OFF_WQT);
  unsigned short* wo_bf  = (unsigned short*)(ws + OFF_WO);
  unsigned short* rpe_bf = (unsigned short*)(ws + OFF_RPE);
  float*          qt     = (float*)         (ws + OFF_QT);
  unsigned short* att_bf = (unsigned short*)(ws + OFF_ATT);
  unsigned short* pm16   = (unsigned short*)(ws + OFF_QRYBF);  // 8MB alias, safe after gemm_proj

  cvt_all<<<dim3(1024, 8), 256, 0, stream>>>(
      query, key, value, Wq, Wk, Wv, Wqt, Wo,
      qry_bf, key_bf, val_bf, wq_bf, wk_bf, wv_bf, wqt_bf, wo_bf);
  rpe_cvt<<<512, 256, 0, stream>>>(rpe, rpe_bf);
  gemm_proj<<<dim3(8, 16, 4), 256, 0, stream>>>(
      qry_bf, key_bf, val_bf, wq_bf, wk_bf, wv_bf, wqt_bf,
      bq, bk, bv, bqt, q_bf, k_bf, vt_bf, qt);
  pack_pm<<<SEQ*SEQ/1024, 256, 0, stream>>>(pos, mask, pm16);
  attn_kernel<<<dim3(SEQ/32, NH), 256, 0, stream>>>(
      q_bf, k_bf, vt_bf, rpe_bf, pm16, att_bf);
  gemm_wo<<<dim3(8, 16), 256, 0, stream>>>(att_bf, wo_bf, bo, qt);
  ln_kernel<<<2048, 256, 0, stream>>>(qt, gamma, beta, out);
}

// Round 4
// 128.224 us; speedup vs baseline: 1.4736x; 1.1413x over previous
//
#include <hip/hip_runtime.h>

// ============================================================================
// SelfAttentionLayer (RPE attention), MI355X bf16-MFMA implementation.
// Pipeline: cvt_all(+rpe) -> gemm_proj(z=0..3: q,k,v,qt) -> pack_pm(permuted) ->
//           attn (4-wave k-split, no-max exp2 softmax, e5m2 qrpe table,
//                 cvt_pk P-pack, ones-MFMA row-sum, pm prefetch, setprio) ->
//           gemm_wo (+qt residual, in-place) -> ln.
// ============================================================================

typedef short          bf16x8 __attribute__((ext_vector_type(8)));
typedef float          f32x4  __attribute__((ext_vector_type(4)));
typedef int            i32x4  __attribute__((ext_vector_type(4)));
typedef unsigned short u16x4  __attribute__((ext_vector_type(4)));
typedef unsigned short u16x8  __attribute__((ext_vector_type(8)));
typedef unsigned int   u32x2  __attribute__((ext_vector_type(2)));

#define SEQ 2048
#define EMB 1024
#define NH  16
#define HD  64
#define RL  512

#define MFMA16(a,b,c) __builtin_amdgcn_mfma_f32_16x16x32_bf16((a),(b),(c),0,0,0)

__device__ __forceinline__ unsigned short f2bf(float f){
  union{float f; unsigned u;} x; x.f=f;
  unsigned r = x.u + 0x7FFFu + ((x.u>>16)&1u);
  return (unsigned short)(r>>16);
}
// pack 2 f32 -> 2 bf16 in one instr
__device__ __forceinline__ unsigned cvtpk(float a, float b){
  unsigned r;
  asm("v_cvt_pk_bf16_f32 %0, %1, %2" : "=v"(r) : "v"(a), "v"(b));
  return r;
}
__device__ __forceinline__ float fexp2(float x){
  float r; asm("v_exp_f32 %0, %1" : "=v"(r) : "v"(x)); return r;
}
// f32 -> e5m2 (RTNE via f16 then round-truncate top byte). Values tiny, no overflow.
__device__ __forceinline__ unsigned char f2e5(float f){
  union{_Float16 h; unsigned short u;} cv; cv.h = (_Float16)f;
  unsigned short b = cv.u;
  unsigned r = (unsigned)b + 0x7Fu + ((b>>8)&1u);
  return (unsigned char)(r>>8);
}
// e5m2 -> f32: byte<<8 is a valid fp16
__device__ __forceinline__ float e52f(unsigned short b){
  union{unsigned short u; _Float16 h;} cv; cv.u = (unsigned short)(b<<8);
  return (float)cv.h;
}
__device__ __forceinline__ void gload16(const void* g, void* l){
  __builtin_amdgcn_global_load_lds((const __attribute__((address_space(1))) unsigned int*)g,
                                   (__attribute__((address_space(3))) unsigned int*)l, 16, 0, 0);
}
// 16B fragment read from a [rows][64]-bf16 LDS tile with per-8-row XOR swizzle.
__device__ __forceinline__ bf16x8 fragld(const unsigned short* t, int row, int chunk){
  int swz = chunk ^ (row & 7);
  return *(const bf16x8*)(t + row*64 + swz*8);
}

// ---------------------------------------------------------------------------
// f32 -> bf16 conversions; y=8 also transposes rpe [l][h][d] -> [h][l][d]
// ---------------------------------------------------------------------------
__global__ __launch_bounds__(256) void cvt_all(
    const float* __restrict__ s0, const float* __restrict__ s1, const float* __restrict__ s2,
    const float* __restrict__ s3, const float* __restrict__ s4, const float* __restrict__ s5,
    const float* __restrict__ s6, const float* __restrict__ s7,
    unsigned short* __restrict__ d0, unsigned short* __restrict__ d1, unsigned short* __restrict__ d2,
    unsigned short* __restrict__ d3, unsigned short* __restrict__ d4, unsigned short* __restrict__ d5,
    unsigned short* __restrict__ d6, unsigned short* __restrict__ d7,
    const float* __restrict__ rpe, unsigned short* __restrict__ rpe_bf)
{
  if (blockIdx.y == 8) {   // rpe transpose+cvt, 4/thread
    int i = (blockIdx.x*256 + threadIdx.x)*4;
    if (i >= RL*NH*HD) return;
    int l = i >> 10, h = (i >> 6) & 15, d = i & 63;
    f32x4 a = *(const f32x4*)(rpe + i);
    u16x4 o;
    #pragma unroll
    for (int j=0;j<4;++j) o[j]=f2bf(a[j]);
    *(u16x4*)(rpe_bf + ((size_t)h*RL + l)*HD + d) = o;
    return;
  }
  const float* s; unsigned short* d; int n;
  switch (blockIdx.y) {
    case 0: s=s0; d=d0; n=SEQ*EMB; break;
    case 1: s=s1; d=d1; n=SEQ*EMB; break;
    case 2: s=s2; d=d2; n=SEQ*EMB; break;
    case 3: s=s3; d=d3; n=EMB*EMB; break;
    case 4: s=s4; d=d4; n=EMB*EMB; break;
    case 5: s=s5; d=d5; n=EMB*EMB; break;
    case 6: s=s6; d=d6; n=EMB*EMB; break;
    default: s=s7; d=d7; n=EMB*EMB; break;
  }
  int i = (blockIdx.x*256 + threadIdx.x)*8;
  if (i >= n) return;
  f32x4 a = *(const f32x4*)(s+i);
  f32x4 b = *(const f32x4*)(s+i+4);
  u16x8 o;
  #pragma unroll
  for (int j=0;j<4;++j){ o[j]=f2bf(a[j]); o[4+j]=f2bf(b[j]); }
  *(u16x8*)(d+i) = o;
}

// ---------------------------------------------------------------------------
// pm16: permuted-within-32 layout so each attn lane reads its 8 entries as one
// 16B load. Within each 32-k group: out_idx = ((k&15)>>2)*8 + ((k>>4)&1)*4 + (k&3).
// masked -> 512 (sentinel column = -inf in table).
// ---------------------------------------------------------------------------
__global__ __launch_bounds__(256) void pack_pm(const int* __restrict__ pos,
                                               const float* __restrict__ mask,
                                               unsigned short* __restrict__ pm)
{
  int i = (blockIdx.x*256 + threadIdx.x)*8;
  i32x4 p0 = *(const i32x4*)(pos + i);
  i32x4 p1 = *(const i32x4*)(pos + i + 4);
  f32x4 m0 = *(const f32x4*)(mask + i);
  f32x4 m1 = *(const f32x4*)(mask + i + 4);
  u16x4 lo, hi;
  #pragma unroll
  for (int j=0;j<4;++j){
    lo[j] = (m0[j] > 0.5f) ? (unsigned short)p0[j] : (unsigned short)512;
    hi[j] = (m1[j] > 0.5f) ? (unsigned short)p1[j] : (unsigned short)512;
  }
  int grp = i & ~31;
  int o0  = ((i & 15) >> 2)*8 + ((i >> 4) & 1)*4;
  *(u16x4*)(pm + grp + o0)     = lo;
  *(u16x4*)(pm + grp + o0 + 8) = hi;
}

// ---------------------------------------------------------------------------
// GEMM core: C[128x128] = A[M,1024] @ W[N,1024]^T  (bf16 in, f32 acc)
// ---------------------------------------------------------------------------
__device__ __forceinline__ void gemm_core(const unsigned short* __restrict__ A,
                                          const unsigned short* __restrict__ W,
                                          unsigned short* At, unsigned short* Wt,
                                          f32x4 acc[4][4], int m0, int n0)
{
  const int tid = threadIdx.x, lane = tid & 63, w = tid >> 6;
  const int rg = lane >> 3, sc = (lane & 7) ^ rg;
  const int c = lane & 15, g = lane >> 4;
  const int wm = w >> 1, wn = w & 1;

  for (int kt = 0; kt < EMB/64; ++kt) {
    __syncthreads();
    #pragma unroll
    for (int i = 0; i < 4; ++i) {
      int r = w*32 + i*8 + rg;
      gload16(A + (size_t)(m0+r)*EMB + kt*64 + sc*8, At + (w*32 + i*8)*64);
      gload16(W + (size_t)(n0+r)*EMB + kt*64 + sc*8, Wt + (w*32 + i*8)*64);
    }
    __syncthreads();
    #pragma unroll
    for (int kk = 0; kk < 2; ++kk) {
      bf16x8 af[4], bw[4];
      #pragma unroll
      for (int mf = 0; mf < 4; ++mf) af[mf] = fragld(At, wm*64 + mf*16 + c, kk*4 + g);
      #pragma unroll
      for (int nf = 0; nf < 4; ++nf) bw[nf] = fragld(Wt, wn*64 + nf*16 + c, kk*4 + g);
      __builtin_amdgcn_s_setprio(1);
      #pragma unroll
      for (int mf = 0; mf < 4; ++mf)
        #pragma unroll
        for (int nf = 0; nf < 4; ++nf)
          acc[mf][nf] = MFMA16(af[mf], bw[nf], acc[mf][nf]);
      __builtin_amdgcn_s_setprio(0);
    }
  }
}

// Fused projections. z: 0=Q(scaled by 2^-3 * log2e), 1=K, 2=V(transposed out), 3=QT(f32 out)
__global__ __launch_bounds__(256) void gemm_proj(
    const unsigned short* __restrict__ Aq, const unsigned short* __restrict__ Ak,
    const unsigned short* __restrict__ Av,
    const unsigned short* __restrict__ Wq, const unsigned short* __restrict__ Wk,
    const unsigned short* __restrict__ Wv, const unsigned short* __restrict__ Wqt,
    const float* __restrict__ bq, const float* __restrict__ bk,
    const float* __restrict__ bv, const float* __restrict__ bqt,
    unsigned short* __restrict__ q_out, unsigned short* __restrict__ k_out,
    unsigned short* __restrict__ vt_out, float* __restrict__ qt_out)
{
  __shared__ alignas(16) unsigned short At[128*64];
  __shared__ alignas(16) unsigned short Wt[128*64];
  const unsigned short *A, *W; const float* bias;
  const int z = blockIdx.z;
  if      (z == 0) { A=Aq; W=Wq;  bias=bq;  }
  else if (z == 1) { A=Ak; W=Wk;  bias=bk;  }
  else if (z == 2) { A=Av; W=Wv;  bias=bv;  }
  else             { A=Aq; W=Wqt; bias=bqt; }

  f32x4 acc[4][4];
  #pragma unroll
  for (int i=0;i<4;++i)
    #pragma unroll
    for (int j=0;j<4;++j) acc[i][j] = (f32x4){0.f,0.f,0.f,0.f};

  const int m0 = blockIdx.y*128, n0 = blockIdx.x*128;
  gemm_core(A, W, At, Wt, acc, m0, n0);

  const int lane = threadIdx.x & 63, w = threadIdx.x >> 6;
  const int c = lane & 15, g = lane >> 4, wm = w >> 1, wn = w & 1;
  const float QSCALE = 0.125f * 1.4426950408889634f;   // HDIM^-0.5 * log2(e)
  #pragma unroll
  for (int nf = 0; nf < 4; ++nf) {
    int n = n0 + wn*64 + nf*16 + c;
    float b = bias[n];
    #pragma unroll
    for (int mf = 0; mf < 4; ++mf) {
      int mb = m0 + wm*64 + mf*16 + g*4;
      if (z == 0) {
        #pragma unroll
        for (int j=0;j<4;++j) q_out[(size_t)(mb+j)*EMB + n] = f2bf((acc[mf][nf][j] + b)*QSCALE);
      } else if (z == 1) {
        #pragma unroll
        for (int j=0;j<4;++j) k_out[(size_t)(mb+j)*EMB + n] = f2bf(acc[mf][nf][j] + b);
      } else if (z == 2) {
        u16x4 pk;
        #pragma unroll
        for (int j=0;j<4;++j) pk[j] = f2bf(acc[mf][nf][j] + b);
        *(u16x4*)(vt_out + (size_t)n*SEQ + mb) = pk;     // V^T layout [n][s]
      } else {
        #pragma unroll
        for (int j=0;j<4;++j) qt_out[(size_t)(mb+j)*EMB + n] = acc[mf][nf][j] + b;
      }
    }
  }
}

// Output projection: qt[m][n] += att @ Wo^T + bo   (in-place residual)
__global__ __launch_bounds__(256) void gemm_wo(
    const unsigned short* __restrict__ A, const unsigned short* __restrict__ W,
    const float* __restrict__ bo, float* __restrict__ qt)
{
  __shared__ alignas(16) unsigned short At[128*64];
  __shared__ alignas(16) unsigned short Wt[128*64];
  f32x4 acc[4][4];
  #pragma unroll
  for (int i=0;i<4;++i)
    #pragma unroll
    for (int j=0;j<4;++j) acc[i][j] = (f32x4){0.f,0.f,0.f,0.f};
  const int m0 = blockIdx.y*128, n0 = blockIdx.x*128;
  gemm_core(A, W, At, Wt, acc, m0, n0);

  const int lane = threadIdx.x & 63, w = threadIdx.x >> 6;
  const int c = lane & 15, g = lane >> 4, wm = w >> 1, wn = w & 1;
  #pragma unroll
  for (int nf = 0; nf < 4; ++nf) {
    int n = n0 + wn*64 + nf*16 + c;
    float b = bo[n];
    #pragma unroll
    for (int mf = 0; mf < 4; ++mf) {
      int mb = m0 + wm*64 + mf*16 + g*4;
      #pragma unroll
      for (int j=0;j<4;++j) {
        size_t idx = (size_t)(mb+j)*EMB + n;
        qt[idx] = acc[mf][nf][j] + b + qt[idx];
      }
    }
  }
}

// ---------------------------------------------------------------------------
// Attention: block = (32 q-rows, 1 head), 4 waves (qh = w&1 -> 16 q-rows,
// ks = w>>1 -> 32-k half of the 64-k tile). Swapped QK^T (mfma(K,Q)),
// no-max exp2 softmax, e5m2 qrpe table (sentinel col 512 = -inf),
// cvt_pk P-pack, ones-MFMA row-sum, 1-tile pm prefetch. LDS 38.1KB.
// ---------------------------------------------------------------------------
__global__ __launch_bounds__(256) void attn_kernel(
    const unsigned short* __restrict__ q_bf, const unsigned short* __restrict__ k_bf,
    const unsigned short* __restrict__ vt_bf, const unsigned short* __restrict__ rpe_bf,
    const unsigned short* __restrict__ pm, unsigned short* __restrict__ att_out)
{
  // pool carve (38144 B):
  //  [0,8192)      k_tile  (64x64 bf16, swizzled)      | red (post-loop alias)
  //  [8192,16384)  vt_tile (64x64 bf16, swizzled)      | red2 (post-loop alias)
  //  [16384,33024) table8  (32 x 520 e5m2)
  //  [33024,38144) q_tile 4KB (prologue) | p_lds 4x640 u16 (loop)
  __shared__ alignas(16) unsigned char pool[38144];
  unsigned short* k_tile  = (unsigned short*)(pool);
  unsigned short* vt_tile = (unsigned short*)(pool + 8192);
  unsigned char*  table8  = pool + 16384;
  unsigned short* q_tile  = (unsigned short*)(pool + 33024);
  unsigned short* p_base  = (unsigned short*)(pool + 33024);
  float*          red     = (float*)(pool);            // [2][64][16]
  float*          red2    = (float*)(pool + 8192);     // [2][4][4]

  const int tid = threadIdx.x, lane = tid & 63, w = tid >> 6;
  const int qh = w & 1, ks = w >> 1;
  const int h = blockIdx.y;
  const int q0 = blockIdx.x * 32;
  const int rg = lane >> 3, sc = (lane & 7) ^ rg;
  const int c = lane & 15, g = lane >> 4;
  const bf16x8 kOnes = {16256,16256,16256,16256,16256,16256,16256,16256}; // bf16 1.0

  // stage Q tile (32 x 64): each wave 8 rows
  gload16(q_bf + (size_t)(q0 + w*8 + rg)*EMB + h*HD + sc*8, q_tile + (w*8)*64);
  __syncthreads();

  // prologue: table[q][l] = q_row . rpe_l  (wave w covers 16 l-rows per chunk)
  for (int ch = 0; ch < 8; ++ch) {
    __syncthreads();
    #pragma unroll
    for (int i = 0; i < 2; ++i)
      gload16(rpe_bf + ((size_t)h*RL + ch*64 + w*16 + i*8 + rg)*HD + sc*8,
              k_tile + (w*16 + i*8)*64);
    __syncthreads();
    #pragma unroll
    for (int qq = 0; qq < 2; ++qq) {
      f32x4 dd = (f32x4){0.f,0.f,0.f,0.f};
      dd = MFMA16(fragld(k_tile, w*16 + c, g),     fragld(q_tile, qq*16 + c, g),     dd);
      dd = MFMA16(fragld(k_tile, w*16 + c, 4 + g), fragld(q_tile, qq*16 + c, 4 + g), dd);
      unsigned pk = (unsigned)f2e5(dd[0]) | ((unsigned)f2e5(dd[1])<<8)
                  | ((unsigned)f2e5(dd[2])<<16) | ((unsigned)f2e5(dd[3])<<24);
      *(unsigned*)(table8 + (qq*16 + c)*520 + ch*64 + w*16 + g*4) = pk;
    }
  }
  // sentinel col 512 = e5m2 -inf (0xFC): masked-out gather target
  if (tid < 32) table8[tid*520 + 512] = 0xFC;

  f32x4 oacc[4];
  #pragma unroll
  for (int i=0;i<4;++i) oacc[i] = (f32x4){0.f,0.f,0.f,0.f};
  f32x4 osum = (f32x4){0.f,0.f,0.f,0.f};
  const bf16x8 qf0 = fragld(q_tile, qh*16 + c, g);
  const bf16x8 qf1 = fragld(q_tile, qh*16 + c, 4 + g);
  unsigned short* pw = p_base + w*640;
  const unsigned char* trow = table8 + (qh*16 + c)*520;
  const unsigned short* pmrow = pm + (size_t)(q0 + qh*16 + c)*SEQ + ks*32 + g*8;

  u16x8 pvv = *(const u16x8*)(pmrow);   // tile 0 indices

  for (int kt = 0; kt < SEQ/64; ++kt) {
    const int kb = kt*64;
    __syncthreads();   // also orders prologue q_tile reads before p_lds alias writes
    #pragma unroll
    for (int i = 0; i < 2; ++i) {
      gload16(k_bf  + (size_t)(kb + w*16 + i*8 + rg)*EMB + h*HD + sc*8, k_tile  + (w*16 + i*8)*64);
      gload16(vt_bf + ((size_t)h*HD + w*16 + i*8 + rg)*SEQ + kb + sc*8, vt_tile + (w*16 + i*8)*64);
    }
    // next tile's pm indices — latency hides under this tile's compute (T14)
    u16x8 pvv_n = *(const u16x8*)(pmrow + ((kb + 64) & (SEQ-1)));
    __syncthreads();

    #pragma unroll
    for (int kf = 0; kf < 2; ++kf) {
      f32x4 sf = (f32x4){0.f,0.f,0.f,0.f};
      __builtin_amdgcn_s_setprio(1);
      sf = MFMA16(fragld(k_tile, ks*32 + kf*16 + c, g),     qf0, sf);
      sf = MFMA16(fragld(k_tile, ks*32 + kf*16 + c, 4 + g), qf1, sf);
      __builtin_amdgcn_s_setprio(0);
      float p0 = fexp2(sf[0] + e52f(trow[pvv[kf*4+0]]));
      float p1 = fexp2(sf[1] + e52f(trow[pvv[kf*4+1]]));
      float p2 = fexp2(sf[2] + e52f(trow[pvv[kf*4+2]]));
      float p3 = fexp2(sf[3] + e52f(trow[pvv[kf*4+3]]));
      u32x2 pk; pk[0] = cvtpk(p0, p1); pk[1] = cvtpk(p2, p3);
      *(u32x2*)(pw + c*40 + kf*16 + g*4) = pk;
    }
    pvv = pvv_n;
    // same-wave LDS RAW: writes complete before fragment read
    asm volatile("s_waitcnt lgkmcnt(0)" ::: "memory");
    bf16x8 pa = *(const bf16x8*)(pw + c*40 + g*8);
    __builtin_amdgcn_s_setprio(1);
    #pragma unroll
    for (int df = 0; df < 4; ++df)
      oacc[df] = MFMA16(pa, fragld(vt_tile, df*16 + c, ks*4 + g), oacc[df]);
    osum = MFMA16(pa, kOnes, osum);   // row-sums: osum[j] = sum_k P[q=g*4+j][k]
    __builtin_amdgcn_s_setprio(0);
  }

  __syncthreads();   // all waves done with k_tile/vt_tile/p_lds before alias reuse
  if (ks) {
    #pragma unroll
    for (int df = 0; df < 4; ++df)
      *(f32x4*)(&red[(qh*64 + lane)*16 + df*4]) = oacc[df];
    if (c == 0) *(f32x4*)(&red2[(qh*4 + g)*4]) = osum;
  }
  __syncthreads();
  if (!ks) {
    osum += *(const f32x4*)(&red2[(qh*4 + g)*4]);
    #pragma unroll
    for (int df = 0; df < 4; ++df)
      oacc[df] += *(const f32x4*)(&red[(qh*64 + lane)*16 + df*4]);
    #pragma unroll
    for (int j = 0; j < 4; ++j) {
      float inv = 1.0f / osum[j];
      int qrow = q0 + qh*16 + g*4 + j;
      #pragma unroll
      for (int df = 0; df < 4; ++df)
        att_out[(size_t)qrow*EMB + h*HD + df*16 + c] = f2bf(oacc[df][j] * inv);
    }
  }
}

// ---------------------------------------------------------------------------
// LayerNorm over rows of qt (f32), gamma/beta, -> d_out
// ---------------------------------------------------------------------------
__global__ __launch_bounds__(256) void ln_kernel(const float* __restrict__ x,
                                                 const float* __restrict__ gamma,
                                                 const float* __restrict__ beta,
                                                 float* __restrict__ out)
{
  const int row = blockIdx.x, t = threadIdx.x;
  f32x4 v = *(const f32x4*)(x + (size_t)row*EMB + t*4);
  float s = v[0]+v[1]+v[2]+v[3];
  #pragma unroll
  for (int o = 32; o > 0; o >>= 1) s += __shfl_xor(s, o);
  __shared__ float r1[4], r2[4];
  if ((t & 63) == 0) r1[t >> 6] = s;
  __syncthreads();
  float mean = (r1[0]+r1[1]+r1[2]+r1[3]) * (1.0f/EMB);
  f32x4 d; float q = 0.f;
  #pragma unroll
  for (int j=0;j<4;++j){ d[j] = v[j] - mean; q += d[j]*d[j]; }
  #pragma unroll
  for (int o = 32; o > 0; o >>= 1) q += __shfl_xor(q, o);
  if ((t & 63) == 0) r2[t >> 6] = q;
  __syncthreads();
  float var = (r2[0]+r2[1]+r2[2]+r2[3]) * (1.0f/EMB);
  float rs = rsqrtf(var + 1e-6f);
  f32x4 gg = *(const f32x4*)(gamma + t*4);
  f32x4 bb = *(const f32x4*)(beta  + t*4);
  f32x4 o4;
  #pragma unroll
  for (int j=0;j<4;++j) o4[j] = d[j]*rs*gg[j] + bb[j];
  *(f32x4*)(out + (size_t)row*EMB + t*4) = o4;
}

// ---------------------------------------------------------------------------
extern "C" void kernel_launch(void* const* d_in, const int* in_sizes, int n_in,
                              void* d_out, int out_size, void* d_ws, size_t ws_size,
                              hipStream_t stream)
{
  (void)in_sizes; (void)n_in; (void)out_size;
  const float* query = (const float*)d_in[0];
  const float* key   = (const float*)d_in[1];
  const float* value = (const float*)d_in[2];
  const int*   pos   = (const int*)  d_in[3];
  const float* mask  = (const float*)d_in[4];
  const float* Wq    = (const float*)d_in[5];
  const float* bq    = (const float*)d_in[6];
  const float* Wk    = (const float*)d_in[7];
  const float* bk    = (const float*)d_in[8];
  const float* Wv    = (const float*)d_in[9];
  const float* bv    = (const float*)d_in[10];
  const float* rpe   = (const float*)d_in[11];
  const float* Wqt   = (const float*)d_in[12];
  const float* bqt   = (const float*)d_in[13];
  const float* Wo    = (const float*)d_in[14];
  const float* bo    = (const float*)d_in[15];
  const float* gamma = (const float*)d_in[16];
  const float* beta  = (const float*)d_in[17];
  float* out = (float*)d_out;

  // workspace layout (bytes)
  char* ws = (char*)d_ws;
  const size_t OFF_QBF   = 0;          // q (scaled)   [2048][1024] bf16  4MB
  const size_t OFF_KBF   = 4194304;    // k            [2048][1024] bf16  4MB
  const size_t OFF_VTBF  = 8388608;    // v^T          [1024][2048] bf16  4MB
  const size_t OFF_QRYBF = 12582912;   // query bf16 4MB (later aliased by pm16)
  const size_t OFF_KEYBF = 16777216;   // key bf16   4MB (later aliased by pm16)
  const size_t OFF_VALBF = 20971520;   // value bf16   4MB
  const size_t OFF_WQ    = 25165824;   // 2MB each
  const size_t OFF_WK    = 27262976;
  const size_t OFF_WV    = 29360128;
  const size_t OFF_WQT   = 31457280;
  const size_t OFF_WO    = 33554432;
  const size_t OFF_RPE   = 35651584;   // [16][512][64] bf16  1MB
  const size_t OFF_QT    = 36700160;   // qt / pre-LN  [2048][1024] f32  8MB
  const size_t OFF_ATT   = 45088768;   // attention out bf16  4MB
  const size_t WS_NEED   = 49283072;
  if (ws_size < WS_NEED) return;  // visible failure instead of OOB writes

  unsigned short* q_bf   = (unsigned short*)(ws + OFF_QBF);
  unsigned short* k_bf   = (unsigned short*)(ws + OFF_KBF);
  unsigned short* vt_bf  = (unsigned short*)(ws + OFF_VTBF);
  unsigned short* qry_bf = (unsigned short*)(ws + OFF_QRYBF);
  unsigned short* key_bf = (unsigned short*)(ws + OFF_KEYBF);
  unsigned short* val_bf = (unsigned short*)(ws + OFF_VALBF);
  unsigned short* wq_bf  = (unsigned short*)(ws + OFF_WQ);
  unsigned short* wk_bf  = (unsigned short*)(ws + OFF_WK);
  unsigned short* wv_bf  = (unsigned short*)(ws + OFF_WV);
  unsigned short* wqt_bf = (unsigned short*)(ws + OFF_WQT);
  unsigned short* wo_bf  = (unsigned short*)(ws + OFF_WO);
  unsigned short* rpe_bf = (unsigned short*)(ws + OFF_RPE);
  float*          qt     = (float*)         (ws + OFF_QT);
  unsigned short* att_bf = (unsigned short*)(ws + OFF_ATT);
  unsigned short* pm16   = (unsigned short*)(ws + OFF_QRYBF);  // 8MB alias, safe after gemm_proj

  cvt_all<<<dim3(1024, 9), 256, 0, stream>>>(
      query, key, value, Wq, Wk, Wv, Wqt, Wo,
      qry_bf, key_bf, val_bf, wq_bf, wk_bf, wv_bf, wqt_bf, wo_bf,
      rpe, rpe_bf);
  gemm_proj<<<dim3(8, 16, 4), 256, 0, stream>>>(
      qry_bf, key_bf, val_bf, wq_bf, wk_bf, wv_bf, wqt_bf,
      bq, bk, bv, bqt, q_bf, k_bf, vt_bf, qt);
  pack_pm<<<SEQ*SEQ/2048, 256, 0, stream>>>(pos, mask, pm16);
  attn_kernel<<<dim3(SEQ/32, NH), 256, 0, stream>>>(
      q_bf, k_bf, vt_bf, rpe_bf, pm16, att_bf);
  gemm_wo<<<dim3(8, 16), 256, 0, stream>>>(att_bf, wo_bf, bo, qt);
  ln_kernel<<<2048, 256, 0, stream>>>(qt, gamma, beta, out);
}